// Round 1
// 973.701 us; speedup vs baseline: 1.2389x; 1.2389x over previous
//
#include <hip/hip_runtime.h>

// ---------------- problem constants ----------------
constexpr int nB = 8, nS = 512, nH = 8, nD = 64, nHID = 512;
constexpr int THOP = 32, TEDGE = 16;
constexpr float SCALE = 0.125f;   // 64^-0.5
constexpr float NEGINF = -30000.0f;

typedef __attribute__((ext_vector_type(8))) short bf16x8;   // 8 bf16 = 4 VGPR
typedef __attribute__((ext_vector_type(4))) float f32x4;

#define MFMA16(A, B, C) __builtin_amdgcn_mfma_f32_16x16x32_bf16(A, B, C, 0, 0, 0)

// ---------------- module-scope scratch ----------------
// hi/lo bf16 split of the projected q/k/v heads (hi+lo ~= fp32 exact)
__device__ __align__(16) unsigned short g_qhi[(size_t)nB * nH * nS * nD];  // [bh][s][d]
__device__ __align__(16) unsigned short g_qlo[(size_t)nB * nH * nS * nD];
__device__ __align__(16) unsigned short g_khi[(size_t)nB * nH * nS * nD];
__device__ __align__(16) unsigned short g_klo[(size_t)nB * nH * nS * nD];
__device__ __align__(16) unsigned short g_vhiT[(size_t)nB * nH * nD * nS]; // [bh][d][s]
__device__ __align__(16) unsigned short g_vloT[(size_t)nB * nH * nD * nS];
// hi/lo bf16 split of q/k hop+edge embeddings: qhe@0, khe@32*512, qee@64*512, kee@80*512
__device__ __align__(16) unsigned short g_embh[96 * 512];
__device__ __align__(16) unsigned short g_embl[96 * 512];
__device__ float g_x[(size_t)nB * nS * nHID];               // attn out [b*s][hid]
// 0:dist64 1:edge64 2:mmode 3:fmode ; dtype flags (0=bf16,1=fp32):
// 4..20 = q,k,v,qhe,qee,khe,kee,vhe,vee,Wq,bq,Wk,bk,Wv,bv,Wo,bo ; 21 = const 1
__device__ int g_flags[32];

// adaptive scalar load: bf16 or fp32 element i
__device__ __forceinline__ float ldf(const void* p, int isf32, size_t i) {
  if (isf32) return ((const float*)p)[i];
  unsigned int w = (unsigned int)(((const unsigned short*)p)[i]) << 16;
  return __uint_as_float(w);
}
__device__ __forceinline__ unsigned short f2bf(float x) {   // RNE
  unsigned u = __float_as_uint(x);
  u += 0x7FFFu + ((u >> 16) & 1u);
  return (unsigned short)(u >> 16);
}
__device__ __forceinline__ float bf2f(unsigned short h) {
  return __uint_as_float((unsigned)h << 16);
}

// ---------------- bool-encoding detection ----------------
__device__ int detect_bool_mode(const unsigned char* p) {
  if (p[0] == 0x80 && p[1] == 0x3F) return 2;   // bf16
  if (p[0] == 0x00 && p[1] == 0x3C) return 4;   // fp16
  if (p[0] == 0x00 && p[3] == 0x3F) return 3;   // fp32
  for (int i = 0; i < 64; i += 4)               // u8 vs int32
    if (p[i + 1] | p[i + 2] | p[i + 3]) return 1;
  return 0;                                     // int32
}
__device__ __forceinline__ bool bool_at(const unsigned char* p, int mode, size_t i) {
  switch (mode) {
    case 0: return ((const int*)p)[i] != 0;
    case 1: return p[i] != 0;
    case 3: return ((const float*)p)[i] != 0.f;
    default: return ((const unsigned short*)p)[i] != 0;  // bf16/fp16
  }
}

// -------- parallel detection: one block per array/task, sampled -------------
__global__ __launch_bounds__(256) void detect_all(
    const void* q, const void* k, const void* v,
    const void* qhe, const void* qee, const void* khe, const void* kee,
    const void* vhe, const void* vee,
    const int* dist, const int* edge,
    const unsigned char* mraw, const unsigned char* fraw,
    const void* Wq, const void* bq, const void* Wk, const void* bk,
    const void* Wv, const void* bv, const void* Wo, const void* bo) {
  __shared__ float sred[256];
  __shared__ int nzs;
  const int tid = threadIdx.x;
  const int blk = blockIdx.x;

  if (blk < 17) {
    const void* arrs[17] = {q, k, v, qhe, qee, khe, kee, vhe, vee,
                            Wq, bq, Wk, bk, Wv, bv, Wo, bo};
    const int full[17] = {2097152, 2097152, 2097152, 8192, 8192, 8192, 8192,
                          8192, 8192, 262144, 512, 262144, 512, 262144, 512,
                          262144, 512};
    const int n = full[blk] < 16384 ? full[blk] : 16384;   // sampled scan
    const unsigned short* u = (const unsigned short*)arrs[blk];
    float m = 0.f;
    for (int i = tid; i < n; i += 256) {
      float x = __uint_as_float((unsigned int)u[i] << 16);
      if (x != x) x = 1e20f;
      m = fmaxf(m, fabsf(x));
    }
    sred[tid] = m;
    __syncthreads();
    for (int s = 128; s > 0; s >>= 1) {
      if (tid < s) sred[tid] = fmaxf(sred[tid], sred[tid + s]);
      __syncthreads();
    }
    if (tid == 0) g_flags[4 + blk] = (sred[0] > 1e3f) ? 1 : 0;
  } else if (blk == 17 || blk == 18) {
    const int* p = (blk == 17) ? dist : edge;
    if (tid == 0) nzs = 0;
    __syncthreads();
    int a = 0;
    for (int i = tid; i < 4096; i += 256) a |= p[2 * i + 1];
    if (a) atomicOr(&nzs, 1);
    __syncthreads();
    if (tid == 0) g_flags[blk - 17] = (nzs == 0);   // all-zero high words -> int64
  } else {
    if (tid == 0) {
      g_flags[2] = detect_bool_mode(mraw);
      g_flags[3] = detect_bool_mode(fraw);
      g_flags[21] = 1;                              // const: g_x is fp32
    }
  }
}

// -------- emb prep: split q/k hop+edge embeddings into bf16 hi/lo ----------
__global__ __launch_bounds__(256) void emb_prep(
    const void* qhe, const void* khe, const void* qee, const void* kee) {
  const int blk = blockIdx.x;  // 0:qhe 1:khe 2:qee 3:kee
  const void* srcs[4] = {qhe, khe, qee, kee};
  const int flagIdx[4] = {7, 9, 8, 10};
  const int counts[4] = {32 * 512, 32 * 512, 16 * 512, 16 * 512};
  const int dsts[4] = {0, 32 * 512, 64 * 512, 80 * 512};
  const int f = g_flags[flagIdx[blk]];
  const void* src = srcs[blk];
  const int n = counts[blk], d0 = dsts[blk];
  for (int i = threadIdx.x; i < n; i += 256) {
    const float x = ldf(src, f, i);
    const unsigned short hi = f2bf(x);
    g_embh[d0 + i] = hi;
    g_embl[d0 + i] = f2bf(x - bf2f(hi));
  }
}

// -------- LDS-tiled fp32 GEMM: C[m,n] = A[m,:] @ W[:,n] + bias[n] -----------
// 64x64 tile / block, 256 threads, 4x4 micro-tile, float4 LDS reads.
// mode 0/1: epilogue -> hi/lo bf16 [bh][s][d] (q / k)
// mode 2:   epilogue -> hi/lo bf16 transposed [bh][d][s] (v)
// mode 3:   fp32 -> dst
__global__ __launch_bounds__(256) void gemm_tiled(
    const void* __restrict__ A, int aFlag,
    const void* __restrict__ W, int wFlag,
    const void* __restrict__ bias, int bFlag,
    float* __restrict__ dst, int mode) {
  __shared__ float As[32][68];
  __shared__ float Ws[32][68];
  const int aF = g_flags[aFlag], wF = g_flags[wFlag], bF = g_flags[bFlag];
  const int tid = threadIdx.x;
  const int m0 = blockIdx.y * 64, n0 = blockIdx.x * 64;
  const int ti = tid & 15, tj = tid >> 4;
  float acc[4][4] = {{0.f}};

  for (int k0 = 0; k0 < 512; k0 += 32) {
    __syncthreads();
#pragma unroll
    for (int i = 0; i < 8; ++i) {
      const int idx = tid + i * 256;
      const int r = idx >> 5, c = idx & 31;
      As[c][r] = ldf(A, aF, (size_t)(m0 + r) * 512 + k0 + c);
      const int kr = idx >> 6, n = idx & 63;
      Ws[kr][n] = ldf(W, wF, (size_t)(k0 + kr) * 512 + n0 + n);
    }
    __syncthreads();
#pragma unroll
    for (int kc = 0; kc < 32; ++kc) {
      const float4 a = *reinterpret_cast<const float4*>(&As[kc][tj * 4]);
      const float4 bb = *reinterpret_cast<const float4*>(&Ws[kc][ti * 4]);
      acc[0][0] += a.x * bb.x; acc[0][1] += a.x * bb.y; acc[0][2] += a.x * bb.z; acc[0][3] += a.x * bb.w;
      acc[1][0] += a.y * bb.x; acc[1][1] += a.y * bb.y; acc[1][2] += a.y * bb.z; acc[1][3] += a.y * bb.w;
      acc[2][0] += a.z * bb.x; acc[2][1] += a.z * bb.y; acc[2][2] += a.z * bb.z; acc[2][3] += a.z * bb.w;
      acc[3][0] += a.w * bb.x; acc[3][1] += a.w * bb.y; acc[3][2] += a.w * bb.z; acc[3][3] += a.w * bb.w;
    }
  }
#pragma unroll
  for (int mi = 0; mi < 4; ++mi)
#pragma unroll
    for (int ni = 0; ni < 4; ++ni) {
      const int m = m0 + tj * 4 + mi;
      const int n = n0 + ti * 4 + ni;
      const float v2 = acc[mi][ni] + ldf(bias, bF, n);
      if (mode == 3) {
        dst[(size_t)m * 512 + n] = v2;
      } else {
        const int b = m >> 9, s = m & 511, h = n >> 6, d = n & 63;
        const unsigned short hi = f2bf(v2);
        const unsigned short lo = f2bf(v2 - bf2f(hi));
        if (mode == 0) {
          const size_t i0 = (((size_t)(b * nH + h) * nS) + s) * nD + d;
          g_qhi[i0] = hi; g_qlo[i0] = lo;
        } else if (mode == 1) {
          const size_t i0 = (((size_t)(b * nH + h) * nS) + s) * nD + d;
          g_khi[i0] = hi; g_klo[i0] = lo;
        } else {
          const size_t i0 = (((size_t)(b * nH + h) * nD) + d) * nS + s;
          g_vhiT[i0] = hi; g_vloT[i0] = lo;
        }
      }
    }
}

// ---------------- fused MFMA attention: one block per (bh, 16-query tile) ---
// 4 waves; wave w owns keys [w*128, w*128+128). Scores kept transposed
// (S^T = mfma(K, Q^T)) so each lane owns one q-column -> register softmax.
__global__ __launch_bounds__(256) void attn_kernel(
    const int* __restrict__ dist, const int* __restrict__ edge,
    const unsigned char* __restrict__ mraw, const unsigned char* __restrict__ fraw,
    const void* __restrict__ vhe, const void* __restrict__ vee) {
  __shared__ float chop_s[16][33];
  __shared__ float cedge_s[16][17];
  __shared__ float vha_s[16][33];
  __shared__ float vea_s[16][17];
  __shared__ float red_s[16][4];
  __shared__ float red2_s[16][4];
  __shared__ float rinv_s[16];
  __shared__ float x_s[64][17];   // out^T partial-sum [d][q]

  const int qt = blockIdx.x, bh = blockIdx.y;
  const int b = bh >> 3, h = bh & 7;
  const int q0 = qt * 16;
  const int tid = threadIdx.x;
  const int w = tid >> 6, l = tid & 63, c = l & 15, g = l >> 4;

  const int d64 = g_flags[0], e64 = g_flags[1];
  const int mmode = g_flags[2], fmode = g_flags[3];
  const int fvhe = g_flags[11], fvee = g_flags[12];

  // zero accumulators in LDS
  for (int i = tid; i < 16 * 33; i += 256) (&vha_s[0][0])[i] = 0.f;
  for (int i = tid; i < 16 * 17; i += 256) (&vea_s[0][0])[i] = 0.f;
  for (int i = tid; i < 64 * 17; i += 256) (&x_s[0][0])[i] = 0.f;

  // Q fragments for this block's 16 query rows (lane: row=c, d=g*8..+7 [+32])
  const size_t qbase = (((size_t)bh * nS) + q0 + c) * nD + g * 8;
  const bf16x8 qh0 = *(const bf16x8*)(g_qhi + qbase);
  const bf16x8 qh1 = *(const bf16x8*)(g_qhi + qbase + 32);
  const bf16x8 ql0 = *(const bf16x8*)(g_qlo + qbase);
  const bf16x8 ql1 = *(const bf16x8*)(g_qlo + qbase + 32);

  // ---- Phase 0: bias tables via MFMA. waves 0,1: hop t 0-15/16-31; wave 2: edge
  if (w < 3) {
    const bool isEdge = (w == 2);
    const int tb = (w == 1) ? 16 : 0;
    const size_t qe0 = (isEdge ? (size_t)64 * 512 : 0) + (size_t)(tb + c) * 512 + h * 64;
    const size_t ke0 = (isEdge ? (size_t)80 * 512 : (size_t)32 * 512) + (size_t)(tb + c) * 512 + h * 64;
    f32x4 acc = {0.f, 0.f, 0.f, 0.f};
#pragma unroll
    for (int dh = 0; dh < 2; ++dh) {
      const bf16x8 qhh = dh ? qh1 : qh0;
      const bf16x8 qll = dh ? ql1 : ql0;
      const bf16x8 khq = *(const bf16x8*)(g_khi + qbase + dh * 32);
      const bf16x8 klq = *(const bf16x8*)(g_klo + qbase + dh * 32);
      const bf16x8 eqh = *(const bf16x8*)(g_embh + qe0 + dh * 32 + g * 8);
      const bf16x8 eql = *(const bf16x8*)(g_embl + qe0 + dh * 32 + g * 8);
      const bf16x8 ekh = *(const bf16x8*)(g_embh + ke0 + dh * 32 + g * 8);
      const bf16x8 ekl = *(const bf16x8*)(g_embl + ke0 + dh * 32 + g * 8);
      acc = MFMA16(qhh, eqh, acc);
      acc = MFMA16(qll, eqh, acc);
      acc = MFMA16(qhh, eql, acc);
      acc = MFMA16(khq, ekh, acc);
      acc = MFMA16(klq, ekh, acc);
      acc = MFMA16(khq, ekl, acc);
    }
    if (!isEdge) {
#pragma unroll
      for (int r = 0; r < 4; ++r) chop_s[4 * g + r][tb + c] = acc[r];
    } else {
#pragma unroll
      for (int r = 0; r < 4; ++r) cedge_s[4 * g + r][c] = acc[r];
    }
  }
  __syncthreads();   // barrier A

  // ---- Phase A: S^T tiles = mfma(K, Q^T) + gathered bias, masked -----------
  f32x4 pS[8];
  unsigned dpack[8], epack[8];
  const size_t rowq = ((size_t)b * nS + q0 + c) * nS;
#pragma unroll
  for (int kt = 0; kt < 8; ++kt) {
    const int kb = w * 128 + kt * 16;
    const size_t kbase = (((size_t)bh * nS) + kb + c) * nD + g * 8;
    f32x4 acc = {0.f, 0.f, 0.f, 0.f};
    {
      const bf16x8 kh0 = *(const bf16x8*)(g_khi + kbase);
      const bf16x8 kl0 = *(const bf16x8*)(g_klo + kbase);
      acc = MFMA16(kh0, qh0, acc);
      acc = MFMA16(kl0, qh0, acc);
      acc = MFMA16(kh0, ql0, acc);
      const bf16x8 kh1 = *(const bf16x8*)(g_khi + kbase + 32);
      const bf16x8 kl1 = *(const bf16x8*)(g_klo + kbase + 32);
      acc = MFMA16(kh1, qh1, acc);
      acc = MFMA16(kl1, qh1, acc);
      acc = MFMA16(kh1, ql1, acc);
    }
    unsigned dp = 0, ep = 0;
#pragma unroll
    for (int r = 0; r < 4; ++r) {
      const int key = kb + 4 * g + r;
      const size_t off = rowq + key;
      const int dv = (d64 ? dist[2 * off] : dist[off]) & (THOP - 1);
      const int ev = (e64 ? edge[2 * off] : edge[off]) & (TEDGE - 1);
      dp |= (unsigned)dv << (5 * r);
      ep |= (unsigned)ev << (4 * r);
      const float s = (acc[r] + chop_s[c][dv] + cedge_s[c][ev]) * SCALE;
      const bool keep = (h < 4) ? bool_at(mraw, mmode, (size_t)b * nS + key)
                                : bool_at(fraw, fmode, off);
      pS[kt][r] = keep ? s : NEGINF;
    }
    dpack[kt] = dp;
    epack[kt] = ep;
  }

  // ---- Phase B: softmax across registers + bin scatter ----------------------
  float mx = NEGINF;
#pragma unroll
  for (int kt = 0; kt < 8; ++kt)
#pragma unroll
    for (int r = 0; r < 4; ++r) mx = fmaxf(mx, pS[kt][r]);
  mx = fmaxf(mx, __shfl_xor(mx, 16));
  mx = fmaxf(mx, __shfl_xor(mx, 32));
  if (l < 16) red_s[c][w] = mx;
  __syncthreads();   // barrier B
  const float M = fmaxf(fmaxf(red_s[c][0], red_s[c][1]),
                        fmaxf(red_s[c][2], red_s[c][3]));
  float sum = 0.f;
#pragma unroll
  for (int kt = 0; kt < 8; ++kt)
#pragma unroll
    for (int r = 0; r < 4; ++r) {
      const float pv = __expf(pS[kt][r] - M);
      pS[kt][r] = pv;
      sum += pv;
      atomicAdd(&vha_s[c][(dpack[kt] >> (5 * r)) & 31], pv);
      atomicAdd(&vea_s[c][(epack[kt] >> (4 * r)) & 15], pv);
    }
  sum += __shfl_xor(sum, 16);
  sum += __shfl_xor(sum, 32);
  if (l < 16) red2_s[c][w] = sum;
  // pack P to bf16 pairs: pk[kt][0]=(r1,r0), pk[kt][1]=(r3,r2)
  int pk[8][2];
#pragma unroll
  for (int kt = 0; kt < 8; ++kt) {
    pk[kt][0] = ((int)f2bf(pS[kt][1]) << 16) | (int)f2bf(pS[kt][0]);
    pk[kt][1] = ((int)f2bf(pS[kt][3]) << 16) | (int)f2bf(pS[kt][2]);
  }
  __syncthreads();   // barrier C
  if (w == 0 && l < 16) {
    const float tot = red2_s[c][0] + red2_s[c][1] + red2_s[c][2] + red2_s[c][3];
    rinv_s[c] = 1.0f / tot;
  }

  // ---- Phase C: out^T += V^T @ P^T (per-wave partial over its 128 keys) ----
  f32x4 oacc[4] = {{0.f, 0.f, 0.f, 0.f}, {0.f, 0.f, 0.f, 0.f},
                   {0.f, 0.f, 0.f, 0.f}, {0.f, 0.f, 0.f, 0.f}};
  const int srcA = ((g & 1) * 2) * 16 + c;
  const int srcB = srcA + 16;
  const bool hi2 = (g >> 1) != 0;
#pragma unroll
  for (int ks = 0; ks < 4; ++ks) {
    // build B-fragment of P^T for keys [ks*32, ks*32+32)
    const int t0d0 = __shfl(pk[2 * ks][0], srcA);
    const int t1d0 = __shfl(pk[2 * ks + 1][0], srcA);
    const int t0d1 = __shfl(pk[2 * ks][1], srcA);
    const int t1d1 = __shfl(pk[2 * ks + 1][1], srcA);
    const int t0d0b = __shfl(pk[2 * ks][0], srcB);
    const int t1d0b = __shfl(pk[2 * ks + 1][0], srcB);
    const int t0d1b = __shfl(pk[2 * ks][1], srcB);
    const int t1d1b = __shfl(pk[2 * ks + 1][1], srcB);
    union { int i[4]; bf16x8 v; } bu;
    bu.i[0] = hi2 ? t1d0 : t0d0;
    bu.i[1] = hi2 ? t1d1 : t0d1;
    bu.i[2] = hi2 ? t1d0b : t0d0b;
    bu.i[3] = hi2 ? t1d1b : t0d1b;
    const int kk = w * 128 + ks * 32;
#pragma unroll
    for (int t = 0; t < 4; ++t) {
      const size_t vbase = (((size_t)bh * nD) + t * 16 + c) * nS + kk + g * 8;
      const bf16x8 vh_ = *(const bf16x8*)(g_vhiT + vbase);
      const bf16x8 vl_ = *(const bf16x8*)(g_vloT + vbase);
      oacc[t] = MFMA16(vh_, bu.v, oacc[t]);
      oacc[t] = MFMA16(vl_, bu.v, oacc[t]);
    }
  }
#pragma unroll
  for (int t = 0; t < 4; ++t)
#pragma unroll
    for (int r = 0; r < 4; ++r)
      atomicAdd(&x_s[t * 16 + 4 * g + r][c], oacc[t][r]);
  __syncthreads();   // barrier D

  // ---- Tail: add bin-embedding terms, normalize, store ----------------------
  {
    const int d = tid & 63, qq = tid >> 6;   // q = qq + 4*j
    float val[4];
#pragma unroll
    for (int j = 0; j < 4; ++j) val[j] = x_s[d][qq + 4 * j];
    for (int t = 0; t < THOP; ++t) {
      const float e = ldf(vhe, fvhe, (size_t)t * nHID + h * 64 + d);
#pragma unroll
      for (int j = 0; j < 4; ++j) val[j] += vha_s[qq + 4 * j][t] * e;
    }
    for (int t = 0; t < TEDGE; ++t) {
      const float e = ldf(vee, fvee, (size_t)t * nHID + h * 64 + d);
#pragma unroll
      for (int j = 0; j < 4; ++j) val[j] += vea_s[qq + 4 * j][t] * e;
    }
#pragma unroll
    for (int j = 0; j < 4; ++j) {
      const int q = qq + 4 * j;
      g_x[((size_t)b * nS + q0 + q) * nHID + h * 64 + d] = val[j] * rinv_s[q];
    }
  }
}

// ---------------- launcher ----------------
extern "C" void kernel_launch(void* const* d_in, const int* in_sizes, int n_in,
                              void* d_out, int out_size, void* d_ws, size_t ws_size,
                              hipStream_t stream) {
  const void* q   = d_in[0];
  const void* k   = d_in[1];
  const void* v   = d_in[2];
  const void* qhe = d_in[3];
  const void* qee = d_in[4];
  const void* khe = d_in[5];
  const void* kee = d_in[6];
  const void* vhe = d_in[7];
  const void* vee = d_in[8];
  const int* dist = (const int*)d_in[9];
  const int* edge = (const int*)d_in[10];
  const unsigned char* mraw = (const unsigned char*)d_in[11];
  const unsigned char* fraw = (const unsigned char*)d_in[12];
  const void* Wq = d_in[13];
  const void* bq = d_in[14];
  const void* Wk = d_in[15];
  const void* bk = d_in[16];
  const void* Wv = d_in[17];
  const void* bv = d_in[18];
  const void* Wo = d_in[19];
  const void* bo = d_in[20];

  detect_all<<<20, 256, 0, stream>>>(q, k, v, qhe, qee, khe, kee, vhe, vee,
                                     dist, edge, mraw, fraw,
                                     Wq, bq, Wk, bk, Wv, bv, Wo, bo);
  emb_prep<<<4, 256, 0, stream>>>(qhe, khe, qee, kee);
  float* x_d;  hipGetSymbolAddress((void**)&x_d,  HIP_SYMBOL(g_x));
  gemm_tiled<<<dim3(8, 64), 256, 0, stream>>>(q, 4, Wq, 13, bq, 14, nullptr, 0);
  gemm_tiled<<<dim3(8, 64), 256, 0, stream>>>(k, 5, Wk, 15, bk, 16, nullptr, 1);
  gemm_tiled<<<dim3(8, 64), 256, 0, stream>>>(v, 6, Wv, 17, bv, 18, nullptr, 2);
  attn_kernel<<<dim3(32, 64), 256, 0, stream>>>(dist, edge, mraw, fraw, vhe, vee);
  gemm_tiled<<<dim3(8, 64), 256, 0, stream>>>(x_d, 21, Wo, 19, bo, 20,
                                              (float*)d_out, 3);
}

// Round 2
// 665.421 us; speedup vs baseline: 1.8128x; 1.4633x over previous
//
#include <hip/hip_runtime.h>

// ---------------- problem constants ----------------
constexpr int nB = 8, nS = 512, nH = 8, nD = 64, nHID = 512;
constexpr int THOP = 32, TEDGE = 16;
constexpr float SCALE = 0.125f;   // 64^-0.5
constexpr float NEGINF = -30000.0f;

typedef __attribute__((ext_vector_type(8))) short bf16x8;   // 8 bf16 = 4 VGPR
typedef __attribute__((ext_vector_type(4))) float f32x4;

#define MFMA16(A, B, C) __builtin_amdgcn_mfma_f32_16x16x32_bf16(A, B, C, 0, 0, 0)

// ---------------- module-scope scratch ----------------
// hi/lo bf16 split of the projected q/k/v heads (hi+lo ~= fp32 exact)
__device__ __align__(16) unsigned short g_qhi[(size_t)nB * nH * nS * nD];  // [bh][s][d]
__device__ __align__(16) unsigned short g_qlo[(size_t)nB * nH * nS * nD];
__device__ __align__(16) unsigned short g_khi[(size_t)nB * nH * nS * nD];
__device__ __align__(16) unsigned short g_klo[(size_t)nB * nH * nS * nD];
__device__ __align__(16) unsigned short g_vhiT[(size_t)nB * nH * nD * nS]; // [bh][d][s]
__device__ __align__(16) unsigned short g_vloT[(size_t)nB * nH * nD * nS];
// hi/lo bf16 split of q/k hop+edge embeddings: qhe@0, khe@32*512, qee@64*512, kee@80*512
__device__ __align__(16) unsigned short g_embh[96 * 512];
__device__ __align__(16) unsigned short g_embl[96 * 512];
__device__ float g_x[(size_t)nB * nS * nHID];               // attn out [b*s][hid]
// 0:dist64 1:edge64 2:mmode 3:fmode ; dtype flags (0=bf16,1=fp32):
// 4..20 = q,k,v,qhe,qee,khe,kee,vhe,vee,Wq,bq,Wk,bk,Wv,bv,Wo,bo ; 21 = const 1
__device__ int g_flags[32];

// adaptive scalar load: bf16 or fp32 element i
__device__ __forceinline__ float ldf(const void* p, int isf32, size_t i) {
  if (isf32) return ((const float*)p)[i];
  unsigned int w = (unsigned int)(((const unsigned short*)p)[i]) << 16;
  return __uint_as_float(w);
}
__device__ __forceinline__ float bf2f(unsigned short h) {
  return __uint_as_float((unsigned)h << 16);
}
// vector load of 4 consecutive elements (i % 4 == 0)
__device__ __forceinline__ float4 ldf4(const void* p, int isf32, size_t i) {
  if (isf32) return ((const float4*)p)[i >> 2];
  const ushort4 u = ((const ushort4*)p)[i >> 2];
  float4 r;
  r.x = bf2f(u.x); r.y = bf2f(u.y); r.z = bf2f(u.z); r.w = bf2f(u.w);
  return r;
}
__device__ __forceinline__ unsigned short f2bf(float x) {   // RNE
  unsigned u = __float_as_uint(x);
  u += 0x7FFFu + ((u >> 16) & 1u);
  return (unsigned short)(u >> 16);
}

// ---------------- bool-encoding detection ----------------
__device__ int detect_bool_mode(const unsigned char* p) {
  if (p[0] == 0x80 && p[1] == 0x3F) return 2;   // bf16
  if (p[0] == 0x00 && p[1] == 0x3C) return 4;   // fp16
  if (p[0] == 0x00 && p[3] == 0x3F) return 3;   // fp32
  for (int i = 0; i < 64; i += 4)               // u8 vs int32
    if (p[i + 1] | p[i + 2] | p[i + 3]) return 1;
  return 0;                                     // int32
}
__device__ __forceinline__ bool bool_at(const unsigned char* p, int mode, size_t i) {
  switch (mode) {
    case 0: return ((const int*)p)[i] != 0;
    case 1: return p[i] != 0;
    case 3: return ((const float*)p)[i] != 0.f;
    default: return ((const unsigned short*)p)[i] != 0;  // bf16/fp16
  }
}

// -------- parallel detection: one block per array/task, sampled -------------
__global__ __launch_bounds__(256) void detect_all(
    const void* q, const void* k, const void* v,
    const void* qhe, const void* qee, const void* khe, const void* kee,
    const void* vhe, const void* vee,
    const int* dist, const int* edge,
    const unsigned char* mraw, const unsigned char* fraw,
    const void* Wq, const void* bq, const void* Wk, const void* bk,
    const void* Wv, const void* bv, const void* Wo, const void* bo) {
  __shared__ float sred[256];
  __shared__ int nzs;
  const int tid = threadIdx.x;
  const int blk = blockIdx.x;

  if (blk < 17) {
    const void* arrs[17] = {q, k, v, qhe, qee, khe, kee, vhe, vee,
                            Wq, bq, Wk, bk, Wv, bv, Wo, bo};
    const int full[17] = {2097152, 2097152, 2097152, 8192, 8192, 8192, 8192,
                          8192, 8192, 262144, 512, 262144, 512, 262144, 512,
                          262144, 512};
    const int n = full[blk] < 16384 ? full[blk] : 16384;   // sampled scan
    const unsigned short* u = (const unsigned short*)arrs[blk];
    float m = 0.f;
    for (int i = tid; i < n; i += 256) {
      float x = __uint_as_float((unsigned int)u[i] << 16);
      if (x != x) x = 1e20f;
      m = fmaxf(m, fabsf(x));
    }
    sred[tid] = m;
    __syncthreads();
    for (int s = 128; s > 0; s >>= 1) {
      if (tid < s) sred[tid] = fmaxf(sred[tid], sred[tid + s]);
      __syncthreads();
    }
    if (tid == 0) g_flags[4 + blk] = (sred[0] > 1e3f) ? 1 : 0;
  } else if (blk == 17 || blk == 18) {
    const int* p = (blk == 17) ? dist : edge;
    if (tid == 0) nzs = 0;
    __syncthreads();
    int a = 0;
    for (int i = tid; i < 4096; i += 256) a |= p[2 * i + 1];
    if (a) atomicOr(&nzs, 1);
    __syncthreads();
    if (tid == 0) g_flags[blk - 17] = (nzs == 0);   // all-zero high words -> int64
  } else {
    if (tid == 0) {
      g_flags[2] = detect_bool_mode(mraw);
      g_flags[3] = detect_bool_mode(fraw);
      g_flags[21] = 1;                              // const: g_x is fp32
    }
  }
}

// -------- emb prep: split q/k hop+edge embeddings into bf16 hi/lo ----------
__global__ __launch_bounds__(256) void emb_prep(
    const void* qhe, const void* khe, const void* qee, const void* kee) {
  const int blk = blockIdx.x;  // 0:qhe 1:khe 2:qee 3:kee
  const void* srcs[4] = {qhe, khe, qee, kee};
  const int flagIdx[4] = {7, 9, 8, 10};
  const int counts[4] = {32 * 512, 32 * 512, 16 * 512, 16 * 512};
  const int dsts[4] = {0, 32 * 512, 64 * 512, 80 * 512};
  const int f = g_flags[flagIdx[blk]];
  const void* src = srcs[blk];
  const int n = counts[blk], d0 = dsts[blk];
  for (int i = threadIdx.x; i < n; i += 256) {
    const float x = ldf(src, f, i);
    const unsigned short hi = f2bf(x);
    g_embh[d0 + i] = hi;
    g_embl[d0 + i] = f2bf(x - bf2f(hi));
  }
}

// -------- MFMA GEMM: C[m,n] = A[m,:] @ W[:,n] + bias[n]  (hi/lo bf16 split) --
// 64x64 tile / block, 4 waves each computing a 32x32 sub-tile. K-step 32.
// 3 MFMA products (hh + hl + lh) give ~fp32 precision.
// mode 0/1: epilogue -> hi/lo bf16 [bh][s][d] (q / k)
// mode 2:   epilogue -> hi/lo bf16 transposed [bh][d][s] (v)
// mode 3:   fp32 -> dst
__global__ __launch_bounds__(256) void gemm_mfma(
    const void* __restrict__ A, int aFlag,
    const void* __restrict__ W, int wFlag,
    const void* __restrict__ bias, int bFlag,
    float* __restrict__ dst, int mode) {
  __shared__ unsigned short As_hi[64][40];   // [m][k], pad 40 (80B rows, 16B-aligned)
  __shared__ unsigned short As_lo[64][40];
  __shared__ unsigned short Wt_hi[64][40];   // [n][k] (transposed W)
  __shared__ unsigned short Wt_lo[64][40];
  const int aF = g_flags[aFlag], wF = g_flags[wFlag], bF = g_flags[bFlag];
  const int tid = threadIdx.x;
  const int m0 = blockIdx.y * 64, n0 = blockIdx.x * 64;
  const int w = tid >> 6, l = tid & 63, c = l & 15, g = l >> 4;
  const int wr = w >> 1, wc = w & 1;

  f32x4 acc[2][2] = {{{0.f, 0.f, 0.f, 0.f}, {0.f, 0.f, 0.f, 0.f}},
                     {{0.f, 0.f, 0.f, 0.f}, {0.f, 0.f, 0.f, 0.f}}};

  for (int k0 = 0; k0 < 512; k0 += 32) {
    __syncthreads();
    // stage A tile (64 m x 32 k) and W^T tile (64 n x 32 k), hi/lo split
#pragma unroll
    for (int i = 0; i < 2; ++i) {
      const int e = tid + i * 256;              // 0..511, 4 elements each
      {   // A: coalesced along k
        const int r = e >> 3, kk = (e & 7) * 4;
        const float4 a4 = ldf4(A, aF, (size_t)(m0 + r) * 512 + k0 + kk);
        const unsigned short h0 = f2bf(a4.x), h1 = f2bf(a4.y);
        const unsigned short h2 = f2bf(a4.z), h3 = f2bf(a4.w);
        *(unsigned*)&As_hi[r][kk]     = (unsigned)h0 | ((unsigned)h1 << 16);
        *(unsigned*)&As_hi[r][kk + 2] = (unsigned)h2 | ((unsigned)h3 << 16);
        const unsigned short l0 = f2bf(a4.x - bf2f(h0));
        const unsigned short l1 = f2bf(a4.y - bf2f(h1));
        const unsigned short l2 = f2bf(a4.z - bf2f(h2));
        const unsigned short l3 = f2bf(a4.w - bf2f(h3));
        *(unsigned*)&As_lo[r][kk]     = (unsigned)l0 | ((unsigned)l1 << 16);
        *(unsigned*)&As_lo[r][kk + 2] = (unsigned)l2 | ((unsigned)l3 << 16);
      }
      {   // W: coalesced along n, scattered transpose-write
        const int kk = e >> 4, nn = (e & 15) * 4;
        const float4 w4 = ldf4(W, wF, (size_t)(k0 + kk) * 512 + n0 + nn);
        const float wv[4] = {w4.x, w4.y, w4.z, w4.w};
#pragma unroll
        for (int t = 0; t < 4; ++t) {
          const unsigned short hh = f2bf(wv[t]);
          Wt_hi[nn + t][kk] = hh;
          Wt_lo[nn + t][kk] = f2bf(wv[t] - bf2f(hh));
        }
      }
    }
    __syncthreads();
#pragma unroll
    for (int mi = 0; mi < 2; ++mi) {
      const bf16x8 ah = *(const bf16x8*)&As_hi[wr * 32 + mi * 16 + c][g * 8];
      const bf16x8 al = *(const bf16x8*)&As_lo[wr * 32 + mi * 16 + c][g * 8];
#pragma unroll
      for (int nj = 0; nj < 2; ++nj) {
        const bf16x8 wh = *(const bf16x8*)&Wt_hi[wc * 32 + nj * 16 + c][g * 8];
        const bf16x8 wl = *(const bf16x8*)&Wt_lo[wc * 32 + nj * 16 + c][g * 8];
        acc[mi][nj] = MFMA16(ah, wh, acc[mi][nj]);
        acc[mi][nj] = MFMA16(al, wh, acc[mi][nj]);
        acc[mi][nj] = MFMA16(ah, wl, acc[mi][nj]);
      }
    }
  }
  // epilogue: D[i][j], lane(c,g) reg r -> i = 4g+r (A-row), j = c (W^T-row)
#pragma unroll
  for (int mi = 0; mi < 2; ++mi)
#pragma unroll
    for (int nj = 0; nj < 2; ++nj)
#pragma unroll
      for (int r = 0; r < 4; ++r) {
        const int m = m0 + wr * 32 + mi * 16 + 4 * g + r;
        const int n = n0 + wc * 32 + nj * 16 + c;
        const float v2 = acc[mi][nj][r] + ldf(bias, bF, n);
        if (mode == 3) {
          dst[(size_t)m * 512 + n] = v2;
        } else {
          const int b = m >> 9, s = m & 511, h = n >> 6, d = n & 63;
          const unsigned short hi = f2bf(v2);
          const unsigned short lo = f2bf(v2 - bf2f(hi));
          if (mode == 0) {
            const size_t i0 = (((size_t)(b * nH + h) * nS) + s) * nD + d;
            g_qhi[i0] = hi; g_qlo[i0] = lo;
          } else if (mode == 1) {
            const size_t i0 = (((size_t)(b * nH + h) * nS) + s) * nD + d;
            g_khi[i0] = hi; g_klo[i0] = lo;
          } else {
            const size_t i0 = (((size_t)(b * nH + h) * nD) + d) * nS + s;
            g_vhiT[i0] = hi; g_vloT[i0] = lo;
          }
        }
      }
}

// ---------------- fused MFMA attention: one block per (bh, 16-query tile) ---
// 4 waves; wave w owns keys [w*128, w*128+128). Scores kept transposed
// (S^T = mfma(K, Q^T)) so each lane owns one q-column -> register softmax.
// dist/edge/mask staged to LDS bytes with coalesced int4 loads (no gathers).
__global__ __launch_bounds__(256, 4) void attn_kernel(
    const int* __restrict__ dist, const int* __restrict__ edge,
    const unsigned char* __restrict__ mraw, const unsigned char* __restrict__ fraw,
    const void* __restrict__ vhe, const void* __restrict__ vee) {
  __shared__ float chop_s[16][33];
  __shared__ float cedge_s[16][17];
  __shared__ float vha_s[16][33];
  __shared__ float vea_s[16][17];
  __shared__ float red_s[16][4];
  __shared__ float red2_s[16][4];
  __shared__ float rinv_s[16];
  __shared__ float x_s[64][17];              // out^T partial-sum [d][q]
  __shared__ unsigned char dlds[16][516];    // dist bins, stride 516 (bank spread)
  __shared__ unsigned char elds[16][516];    // edge bins
  __shared__ unsigned char flds[16][516];    // focal mask bytes (h>=4)
  __shared__ unsigned char smask_l[516];     // node mask bytes (h<4)

  const int qt = blockIdx.x, bh = blockIdx.y;
  const int b = bh >> 3, h = bh & 7;
  const int q0 = qt * 16;
  const int tid = threadIdx.x;
  const int w = tid >> 6, l = tid & 63, c = l & 15, g = l >> 4;

  const int d64 = g_flags[0], e64 = g_flags[1];
  const int mmode = g_flags[2], fmode = g_flags[3];
  const int fvhe = g_flags[11], fvee = g_flags[12];

  // zero accumulators in LDS
  for (int i = tid; i < 16 * 33; i += 256) (&vha_s[0][0])[i] = 0.f;
  for (int i = tid; i < 16 * 17; i += 256) (&vea_s[0][0])[i] = 0.f;
  for (int i = tid; i < 64 * 17; i += 256) (&x_s[0][0])[i] = 0.f;

  // ---- stage dist/edge bins + masks into LDS (coalesced) -------------------
  const size_t rowbase = ((size_t)b * nS + q0) * nS;
  if (!d64) {
    const int4* dp = (const int4*)(dist + rowbase);
    for (int j4 = tid; j4 < 2048; j4 += 256) {
      const int4 t = dp[j4];
      const int j = j4 * 4, r = j >> 9, c1 = j & 511;
      *(unsigned*)&dlds[r][c1] =
          (unsigned)(t.x & 31) | ((unsigned)(t.y & 31) << 8) |
          ((unsigned)(t.z & 31) << 16) | ((unsigned)(t.w & 31) << 24);
    }
  } else {
    const int4* dp = (const int4*)(dist + 2 * rowbase);
    for (int j2 = tid; j2 < 4096; j2 += 256) {
      const int4 t = dp[j2];
      const int j = j2 * 2, r = j >> 9, c1 = j & 511;
      *(unsigned short*)&dlds[r][c1] =
          (unsigned short)((t.x & 31) | ((t.z & 31) << 8));
    }
  }
  if (!e64) {
    const int4* ep = (const int4*)(edge + rowbase);
    for (int j4 = tid; j4 < 2048; j4 += 256) {
      const int4 t = ep[j4];
      const int j = j4 * 4, r = j >> 9, c1 = j & 511;
      *(unsigned*)&elds[r][c1] =
          (unsigned)(t.x & 15) | ((unsigned)(t.y & 15) << 8) |
          ((unsigned)(t.z & 15) << 16) | ((unsigned)(t.w & 15) << 24);
    }
  } else {
    const int4* ep = (const int4*)(edge + 2 * rowbase);
    for (int j2 = tid; j2 < 4096; j2 += 256) {
      const int4 t = ep[j2];
      const int j = j2 * 2, r = j >> 9, c1 = j & 511;
      *(unsigned short*)&elds[r][c1] =
          (unsigned short)((t.x & 15) | ((t.z & 15) << 8));
    }
  }
  if (h < 4) {
    for (int i4 = tid; i4 < 128; i4 += 256) {
      unsigned wv = 0;
#pragma unroll
      for (int t = 0; t < 4; ++t)
        wv |= (unsigned)bool_at(mraw, mmode, (size_t)b * nS + i4 * 4 + t) << (8 * t);
      *(unsigned*)&smask_l[i4 * 4] = wv;
    }
  } else {
    for (int i4 = tid; i4 < 2048; i4 += 256) {
      const int j = i4 * 4, r = j >> 9, c1 = j & 511;
      unsigned wv = 0;
#pragma unroll
      for (int t = 0; t < 4; ++t)
        wv |= (unsigned)bool_at(fraw, fmode, rowbase + j + t) << (8 * t);
      *(unsigned*)&flds[r][c1] = wv;
    }
  }

  // Q fragments for this block's 16 query rows (lane: row=c, d=g*8..+7 [+32])
  const size_t qbase = (((size_t)bh * nS) + q0 + c) * nD + g * 8;
  const bf16x8 qh0 = *(const bf16x8*)(g_qhi + qbase);
  const bf16x8 qh1 = *(const bf16x8*)(g_qhi + qbase + 32);
  const bf16x8 ql0 = *(const bf16x8*)(g_qlo + qbase);
  const bf16x8 ql1 = *(const bf16x8*)(g_qlo + qbase + 32);

  // ---- Phase 0: bias tables via MFMA. waves 0,1: hop t 0-15/16-31; wave 2: edge
  if (w < 3) {
    const bool isEdge = (w == 2);
    const int tb = (w == 1) ? 16 : 0;
    const size_t qe0 = (isEdge ? (size_t)64 * 512 : 0) + (size_t)(tb + c) * 512 + h * 64;
    const size_t ke0 = (isEdge ? (size_t)80 * 512 : (size_t)32 * 512) + (size_t)(tb + c) * 512 + h * 64;
    f32x4 acc = {0.f, 0.f, 0.f, 0.f};
#pragma unroll
    for (int dh = 0; dh < 2; ++dh) {
      const bf16x8 qhh = dh ? qh1 : qh0;
      const bf16x8 qll = dh ? ql1 : ql0;
      const bf16x8 khq = *(const bf16x8*)(g_khi + qbase + dh * 32);
      const bf16x8 klq = *(const bf16x8*)(g_klo + qbase + dh * 32);
      const bf16x8 eqh = *(const bf16x8*)(g_embh + qe0 + dh * 32 + g * 8);
      const bf16x8 eql = *(const bf16x8*)(g_embl + qe0 + dh * 32 + g * 8);
      const bf16x8 ekh = *(const bf16x8*)(g_embh + ke0 + dh * 32 + g * 8);
      const bf16x8 ekl = *(const bf16x8*)(g_embl + ke0 + dh * 32 + g * 8);
      acc = MFMA16(qhh, eqh, acc);
      acc = MFMA16(qll, eqh, acc);
      acc = MFMA16(qhh, eql, acc);
      acc = MFMA16(khq, ekh, acc);
      acc = MFMA16(klq, ekh, acc);
      acc = MFMA16(khq, ekl, acc);
    }
    if (!isEdge) {
#pragma unroll
      for (int r = 0; r < 4; ++r) chop_s[4 * g + r][tb + c] = acc[r];
    } else {
#pragma unroll
      for (int r = 0; r < 4; ++r) cedge_s[4 * g + r][c] = acc[r];
    }
  }
  __syncthreads();   // barrier A

  // ---- Phase A: S^T tiles = mfma(K, Q^T) + staged bias, masked -------------
  f32x4 pS[8];
  const int kbw = w * 128;
#pragma unroll
  for (int kt = 0; kt < 8; ++kt) {
    const int kb = kbw + kt * 16;
    const size_t kbase = (((size_t)bh * nS) + kb + c) * nD + g * 8;
    f32x4 acc = {0.f, 0.f, 0.f, 0.f};
    {
      const bf16x8 kh0 = *(const bf16x8*)(g_khi + kbase);
      const bf16x8 kl0 = *(const bf16x8*)(g_klo + kbase);
      acc = MFMA16(kh0, qh0, acc);
      acc = MFMA16(kl0, qh0, acc);
      acc = MFMA16(kh0, ql0, acc);
      const bf16x8 kh1 = *(const bf16x8*)(g_khi + kbase + 32);
      const bf16x8 kl1 = *(const bf16x8*)(g_klo + kbase + 32);
      acc = MFMA16(kh1, qh1, acc);
      acc = MFMA16(kl1, qh1, acc);
      acc = MFMA16(kh1, ql1, acc);
    }
    const int key0 = kb + 4 * g;
    const unsigned dw = *(const unsigned*)&dlds[c][key0];
    const unsigned ew = *(const unsigned*)&elds[c][key0];
    const unsigned fw = (h < 4) ? *(const unsigned*)&smask_l[key0]
                                : *(const unsigned*)&flds[c][key0];
#pragma unroll
    for (int r = 0; r < 4; ++r) {
      const int dv = (dw >> (8 * r)) & 255;
      const int ev = (ew >> (8 * r)) & 255;
      const float s = (acc[r] + chop_s[c][dv] + cedge_s[c][ev]) * SCALE;
      pS[kt][r] = ((fw >> (8 * r)) & 255) ? s : NEGINF;
    }
  }

  // ---- Phase B: softmax across registers + bin scatter ----------------------
  float mx = NEGINF;
#pragma unroll
  for (int kt = 0; kt < 8; ++kt)
#pragma unroll
    for (int r = 0; r < 4; ++r) mx = fmaxf(mx, pS[kt][r]);
  mx = fmaxf(mx, __shfl_xor(mx, 16));
  mx = fmaxf(mx, __shfl_xor(mx, 32));
  if (l < 16) red_s[c][w] = mx;
  __syncthreads();   // barrier B
  const float M = fmaxf(fmaxf(red_s[c][0], red_s[c][1]),
                        fmaxf(red_s[c][2], red_s[c][3]));
  float sum = 0.f;
#pragma unroll
  for (int kt = 0; kt < 8; ++kt) {
    const int key0 = kbw + kt * 16 + 4 * g;
    const unsigned dw = *(const unsigned*)&dlds[c][key0];
    const unsigned ew = *(const unsigned*)&elds[c][key0];
#pragma unroll
    for (int r = 0; r < 4; ++r) {
      const float pv = __expf(pS[kt][r] - M);
      pS[kt][r] = pv;
      sum += pv;
      atomicAdd(&vha_s[c][(dw >> (8 * r)) & 255], pv);
      atomicAdd(&vea_s[c][(ew >> (8 * r)) & 255], pv);
    }
  }
  sum += __shfl_xor(sum, 16);
  sum += __shfl_xor(sum, 32);
  if (l < 16) red2_s[c][w] = sum;
  // pack P to bf16 pairs: pk[kt][0]=(r1,r0), pk[kt][1]=(r3,r2)
  int pk[8][2];
#pragma unroll
  for (int kt = 0; kt < 8; ++kt) {
    pk[kt][0] = ((int)f2bf(pS[kt][1]) << 16) | (int)f2bf(pS[kt][0]);
    pk[kt][1] = ((int)f2bf(pS[kt][3]) << 16) | (int)f2bf(pS[kt][2]);
  }
  __syncthreads();   // barrier C
  if (w == 0 && l < 16) {
    const float tot = red2_s[c][0] + red2_s[c][1] + red2_s[c][2] + red2_s[c][3];
    rinv_s[c] = 1.0f / tot;
  }

  // ---- Phase C: out^T += V^T @ P^T (per-wave partial over its 128 keys) ----
  f32x4 oacc[4] = {{0.f, 0.f, 0.f, 0.f}, {0.f, 0.f, 0.f, 0.f},
                   {0.f, 0.f, 0.f, 0.f}, {0.f, 0.f, 0.f, 0.f}};
  const int srcA = ((g & 1) * 2) * 16 + c;
  const int srcB = srcA + 16;
  const bool hi2 = (g >> 1) != 0;
#pragma unroll
  for (int ks = 0; ks < 4; ++ks) {
    // build B-fragment of P^T for keys [ks*32, ks*32+32)
    const int t0d0 = __shfl(pk[2 * ks][0], srcA);
    const int t1d0 = __shfl(pk[2 * ks + 1][0], srcA);
    const int t0d1 = __shfl(pk[2 * ks][1], srcA);
    const int t1d1 = __shfl(pk[2 * ks + 1][1], srcA);
    const int t0d0b = __shfl(pk[2 * ks][0], srcB);
    const int t1d0b = __shfl(pk[2 * ks + 1][0], srcB);
    const int t0d1b = __shfl(pk[2 * ks][1], srcB);
    const int t1d1b = __shfl(pk[2 * ks + 1][1], srcB);
    union { int i[4]; bf16x8 v; } bu;
    bu.i[0] = hi2 ? t1d0 : t0d0;
    bu.i[1] = hi2 ? t1d1 : t0d1;
    bu.i[2] = hi2 ? t1d0b : t0d0b;
    bu.i[3] = hi2 ? t1d1b : t0d1b;
    const int kk = w * 128 + ks * 32;
#pragma unroll
    for (int t = 0; t < 4; ++t) {
      const size_t vbase = (((size_t)bh * nD) + t * 16 + c) * nS + kk + g * 8;
      const bf16x8 vh_ = *(const bf16x8*)(g_vhiT + vbase);
      const bf16x8 vl_ = *(const bf16x8*)(g_vloT + vbase);
      oacc[t] = MFMA16(vh_, bu.v, oacc[t]);
      oacc[t] = MFMA16(vl_, bu.v, oacc[t]);
    }
  }
#pragma unroll
  for (int t = 0; t < 4; ++t)
#pragma unroll
    for (int r = 0; r < 4; ++r)
      atomicAdd(&x_s[t * 16 + 4 * g + r][c], oacc[t][r]);
  __syncthreads();   // barrier D

  // ---- Tail: add bin-embedding terms, normalize, store ----------------------
  {
    const int d = tid & 63, qq = tid >> 6;   // q = qq + 4*j
    float val[4];
#pragma unroll
    for (int j = 0; j < 4; ++j) val[j] = x_s[d][qq + 4 * j];
    for (int t = 0; t < THOP; ++t) {
      const float e = ldf(vhe, fvhe, (size_t)t * nHID + h * 64 + d);
#pragma unroll
      for (int j = 0; j < 4; ++j) val[j] += vha_s[qq + 4 * j][t] * e;
    }
    for (int t = 0; t < TEDGE; ++t) {
      const float e = ldf(vee, fvee, (size_t)t * nHID + h * 64 + d);
#pragma unroll
      for (int j = 0; j < 4; ++j) val[j] += vea_s[qq + 4 * j][t] * e;
    }
#pragma unroll
    for (int j = 0; j < 4; ++j) {
      const int q = qq + 4 * j;
      g_x[((size_t)b * nS + q0 + q) * nHID + h * 64 + d] = val[j] * rinv_s[q];
    }
  }
}

// ---------------- launcher ----------------
extern "C" void kernel_launch(void* const* d_in, const int* in_sizes, int n_in,
                              void* d_out, int out_size, void* d_ws, size_t ws_size,
                              hipStream_t stream) {
  const void* q   = d_in[0];
  const void* k   = d_in[1];
  const void* v   = d_in[2];
  const void* qhe = d_in[3];
  const void* qee = d_in[4];
  const void* khe = d_in[5];
  const void* kee = d_in[6];
  const void* vhe = d_in[7];
  const void* vee = d_in[8];
  const int* dist = (const int*)d_in[9];
  const int* edge = (const int*)d_in[10];
  const unsigned char* mraw = (const unsigned char*)d_in[11];
  const unsigned char* fraw = (const unsigned char*)d_in[12];
  const void* Wq = d_in[13];
  const void* bq = d_in[14];
  const void* Wk = d_in[15];
  const void* bk = d_in[16];
  const void* Wv = d_in[17];
  const void* bv = d_in[18];
  const void* Wo = d_in[19];
  const void* bo = d_in[20];

  detect_all<<<20, 256, 0, stream>>>(q, k, v, qhe, qee, khe, kee, vhe, vee,
                                     dist, edge, mraw, fraw,
                                     Wq, bq, Wk, bk, Wv, bv, Wo, bo);
  emb_prep<<<4, 256, 0, stream>>>(qhe, khe, qee, kee);
  float* x_d;  hipGetSymbolAddress((void**)&x_d,  HIP_SYMBOL(g_x));
  gemm_mfma<<<dim3(8, 64), 256, 0, stream>>>(q, 4, Wq, 13, bq, 14, nullptr, 0);
  gemm_mfma<<<dim3(8, 64), 256, 0, stream>>>(k, 5, Wk, 15, bk, 16, nullptr, 1);
  gemm_mfma<<<dim3(8, 64), 256, 0, stream>>>(v, 6, Wv, 17, bv, 18, nullptr, 2);
  attn_kernel<<<dim3(32, 64), 256, 0, stream>>>(dist, edge, mraw, fraw, vhe, vee);
  gemm_mfma<<<dim3(8, 64), 256, 0, stream>>>(x_d, 21, Wo, 19, bo, 20,
                                             (float*)d_out, 3);
}

// Round 3
// 661.829 us; speedup vs baseline: 1.8227x; 1.0054x over previous
//
#include <hip/hip_runtime.h>

// ---------------- problem constants ----------------
constexpr int nB = 8, nS = 512, nH = 8, nD = 64, nHID = 512;
constexpr int THOP = 32, TEDGE = 16;
constexpr float SCALE = 0.125f;   // 64^-0.5
constexpr float NEGINF = -30000.0f;

typedef __attribute__((ext_vector_type(8))) short bf16x8;   // 8 bf16 = 4 VGPR
typedef __attribute__((ext_vector_type(4))) float f32x4;

#define MFMA16(A, B, C) __builtin_amdgcn_mfma_f32_16x16x32_bf16(A, B, C, 0, 0, 0)

// ---------------- module-scope scratch ----------------
// hi/lo bf16 split of the projected q/k/v heads (hi+lo ~= fp32 exact)
__device__ __align__(16) unsigned short g_qhi[(size_t)nB * nH * nS * nD];  // [bh][s][d]
__device__ __align__(16) unsigned short g_qlo[(size_t)nB * nH * nS * nD];
__device__ __align__(16) unsigned short g_khi[(size_t)nB * nH * nS * nD];
__device__ __align__(16) unsigned short g_klo[(size_t)nB * nH * nS * nD];
__device__ __align__(16) unsigned short g_vhiT[(size_t)nB * nH * nD * nS]; // [bh][d][s]
__device__ __align__(16) unsigned short g_vloT[(size_t)nB * nH * nD * nS];
// hi/lo bf16 split of q/k hop+edge embeddings: qhe@0, khe@32*512, qee@64*512, kee@80*512
__device__ __align__(16) unsigned short g_embh[96 * 512];
__device__ __align__(16) unsigned short g_embl[96 * 512];
// pre-split GEMM inputs: q,k,v flattened [3][2M]
__device__ __align__(16) unsigned short g_inhi[(size_t)3 * 2097152];
__device__ __align__(16) unsigned short g_inlo[(size_t)3 * 2097152];
// pre-transposed+split weights W^T [mat][n][k], mats {Wq,Wk,Wv,Wo}
__device__ __align__(16) unsigned short g_wth[(size_t)4 * 262144];
__device__ __align__(16) unsigned short g_wtl[(size_t)4 * 262144];
// attn output, hi/lo bf16 [b*s][hid]
__device__ __align__(16) unsigned short g_xhi[(size_t)nB * nS * nHID];
__device__ __align__(16) unsigned short g_xlo[(size_t)nB * nS * nHID];
// 0:dist64 1:edge64 2:mmode 3:fmode ; dtype flags (0=bf16,1=fp32):
// 4..20 = q,k,v,qhe,qee,khe,kee,vhe,vee,Wq,bq,Wk,bk,Wv,bv,Wo,bo
__device__ int g_flags[32];

// adaptive scalar load: bf16 or fp32 element i
__device__ __forceinline__ float ldf(const void* p, int isf32, size_t i) {
  if (isf32) return ((const float*)p)[i];
  unsigned int w = (unsigned int)(((const unsigned short*)p)[i]) << 16;
  return __uint_as_float(w);
}
__device__ __forceinline__ float bf2f(unsigned short h) {
  return __uint_as_float((unsigned)h << 16);
}
// vector load of 4 consecutive elements (i % 4 == 0)
__device__ __forceinline__ float4 ldf4(const void* p, int isf32, size_t i) {
  if (isf32) return ((const float4*)p)[i >> 2];
  const ushort4 u = ((const ushort4*)p)[i >> 2];
  float4 r;
  r.x = bf2f(u.x); r.y = bf2f(u.y); r.z = bf2f(u.z); r.w = bf2f(u.w);
  return r;
}
__device__ __forceinline__ unsigned short f2bf(float x) {   // RNE
  unsigned u = __float_as_uint(x);
  u += 0x7FFFu + ((u >> 16) & 1u);
  return (unsigned short)(u >> 16);
}

// ---------------- bool-encoding detection ----------------
__device__ int detect_bool_mode(const unsigned char* p) {
  if (p[0] == 0x80 && p[1] == 0x3F) return 2;   // bf16
  if (p[0] == 0x00 && p[1] == 0x3C) return 4;   // fp16
  if (p[0] == 0x00 && p[3] == 0x3F) return 3;   // fp32
  for (int i = 0; i < 64; i += 4)               // u8 vs int32
    if (p[i + 1] | p[i + 2] | p[i + 3]) return 1;
  return 0;                                     // int32
}
__device__ __forceinline__ bool bool_at(const unsigned char* p, int mode, size_t i) {
  switch (mode) {
    case 0: return ((const int*)p)[i] != 0;
    case 1: return p[i] != 0;
    case 3: return ((const float*)p)[i] != 0.f;
    default: return ((const unsigned short*)p)[i] != 0;  // bf16/fp16
  }
}

// -------- parallel detection: one block per array/task, sampled -------------
__global__ __launch_bounds__(256) void detect_all(
    const void* q, const void* k, const void* v,
    const void* qhe, const void* qee, const void* khe, const void* kee,
    const void* vhe, const void* vee,
    const int* dist, const int* edge,
    const unsigned char* mraw, const unsigned char* fraw,
    const void* Wq, const void* bq, const void* Wk, const void* bk,
    const void* Wv, const void* bv, const void* Wo, const void* bo) {
  __shared__ float sred[256];
  __shared__ int nzs;
  const int tid = threadIdx.x;
  const int blk = blockIdx.x;

  if (blk < 17) {
    const void* arrs[17] = {q, k, v, qhe, qee, khe, kee, vhe, vee,
                            Wq, bq, Wk, bk, Wv, bv, Wo, bo};
    const int full[17] = {2097152, 2097152, 2097152, 8192, 8192, 8192, 8192,
                          8192, 8192, 262144, 512, 262144, 512, 262144, 512,
                          262144, 512};
    const int n = full[blk] < 16384 ? full[blk] : 16384;   // sampled scan
    const unsigned short* u = (const unsigned short*)arrs[blk];
    float m = 0.f;
    for (int i = tid; i < n; i += 256) {
      float x = __uint_as_float((unsigned int)u[i] << 16);
      if (x != x) x = 1e20f;
      m = fmaxf(m, fabsf(x));
    }
    sred[tid] = m;
    __syncthreads();
    for (int s = 128; s > 0; s >>= 1) {
      if (tid < s) sred[tid] = fmaxf(sred[tid], sred[tid + s]);
      __syncthreads();
    }
    if (tid == 0) g_flags[4 + blk] = (sred[0] > 1e3f) ? 1 : 0;
  } else if (blk == 17 || blk == 18) {
    const int* p = (blk == 17) ? dist : edge;
    if (tid == 0) nzs = 0;
    __syncthreads();
    int a = 0;
    for (int i = tid; i < 4096; i += 256) a |= p[2 * i + 1];
    if (a) atomicOr(&nzs, 1);
    __syncthreads();
    if (tid == 0) g_flags[blk - 17] = (nzs == 0);   // all-zero high words -> int64
  } else {
    if (tid == 0) {
      g_flags[2] = detect_bool_mode(mraw);
      g_flags[3] = detect_bool_mode(fraw);
    }
  }
}

// -------- emb prep: split q/k hop+edge embeddings into bf16 hi/lo ----------
__global__ __launch_bounds__(256) void emb_prep(
    const void* qhe, const void* khe, const void* qee, const void* kee) {
  const int blk = blockIdx.x;  // 0:qhe 1:khe 2:qee 3:kee
  const void* srcs[4] = {qhe, khe, qee, kee};
  const int flagIdx[4] = {7, 9, 8, 10};
  const int counts[4] = {32 * 512, 32 * 512, 16 * 512, 16 * 512};
  const int dsts[4] = {0, 32 * 512, 64 * 512, 80 * 512};
  const int f = g_flags[flagIdx[blk]];
  const void* src = srcs[blk];
  const int n = counts[blk], d0 = dsts[blk];
  for (int i = threadIdx.x; i < n; i += 256) {
    const float x = ldf(src, f, i);
    const unsigned short hi = f2bf(x);
    g_embh[d0 + i] = hi;
    g_embl[d0 + i] = f2bf(x - bf2f(hi));
  }
}

// -------- split q/k/v inputs into bf16 hi/lo (once) -------------------------
__global__ __launch_bounds__(256) void split_prep(
    const void* q, const void* k, const void* v) {
  const int t = blockIdx.y;
  const void* srcs[3] = {q, k, v};
  const int f = g_flags[4 + t];
  const size_t base = (size_t)t * 2097152;
  const size_t i = ((size_t)blockIdx.x * 256 + threadIdx.x) * 4;
  const float4 v4 = ldf4(srcs[t], f, i);
  ushort4 h4, l4;
  h4.x = f2bf(v4.x); l4.x = f2bf(v4.x - bf2f(h4.x));
  h4.y = f2bf(v4.y); l4.y = f2bf(v4.y - bf2f(h4.y));
  h4.z = f2bf(v4.z); l4.z = f2bf(v4.z - bf2f(h4.z));
  h4.w = f2bf(v4.w); l4.w = f2bf(v4.w - bf2f(h4.w));
  *(ushort4*)&g_inhi[base + i] = h4;
  *(ushort4*)&g_inlo[base + i] = l4;
}

// -------- transpose + split weights: W[k][n] -> W^T[n][k] hi/lo (once) ------
__global__ __launch_bounds__(256) void wt_prep(
    const void* Wq, const void* Wk, const void* Wv, const void* Wo) {
  __shared__ float t[64][65];
  const int mat = blockIdx.y;
  const void* srcs[4] = {Wq, Wk, Wv, Wo};
  const int fIdx[4] = {13, 15, 17, 19};
  const int f = g_flags[fIdx[mat]];
  const void* W = srcs[mat];
  const int k0 = (blockIdx.x >> 3) * 64, n0 = (blockIdx.x & 7) * 64;
  const int tid = threadIdx.x;
  const int r = tid >> 4, c4 = (tid & 15) * 4;
#pragma unroll
  for (int i = 0; i < 4; ++i) {
    const float4 v4 = ldf4(W, f, (size_t)(k0 + r + i * 16) * 512 + n0 + c4);
    t[r + i * 16][c4] = v4.x;
    t[r + i * 16][c4 + 1] = v4.y;
    t[r + i * 16][c4 + 2] = v4.z;
    t[r + i * 16][c4 + 3] = v4.w;
  }
  __syncthreads();
  unsigned short* dh = g_wth + (size_t)mat * 262144;
  unsigned short* dl = g_wtl + (size_t)mat * 262144;
#pragma unroll
  for (int i = 0; i < 4; ++i) {
    const int rn = r + i * 16;
    ushort4 h4, l4;
    const float v0 = t[c4][rn], v1 = t[c4 + 1][rn];
    const float v2 = t[c4 + 2][rn], v3 = t[c4 + 3][rn];
    h4.x = f2bf(v0); l4.x = f2bf(v0 - bf2f(h4.x));
    h4.y = f2bf(v1); l4.y = f2bf(v1 - bf2f(h4.y));
    h4.z = f2bf(v2); l4.z = f2bf(v2 - bf2f(h4.z));
    h4.w = f2bf(v3); l4.w = f2bf(v3 - bf2f(h4.w));
    *(ushort4*)&dh[(size_t)(n0 + rn) * 512 + k0 + c4] = h4;
    *(ushort4*)&dl[(size_t)(n0 + rn) * 512 + k0 + c4] = l4;
  }
}

// -------- MFMA GEMM: C[m,n] = A[m,:] @ W[:,n] + bias[n]  (pre-split bf16) ---
// 64x64 tile / block, 4 waves each computing a 32x32 sub-tile. K-step 32.
// 3 MFMA products (hh + hl + lh) give ~fp32 precision. Staging = pure copies.
// mode 0/1: epilogue -> hi/lo bf16 [bh][s][d] (q / k)
// mode 2:   epilogue -> hi/lo bf16 transposed [bh][d][s] (v)
// mode 3:   fp32 -> dst
__global__ __launch_bounds__(256) void gemm_mfma(
    const unsigned short* __restrict__ Ahi, const unsigned short* __restrict__ Alo,
    const unsigned short* __restrict__ Wth, const unsigned short* __restrict__ Wtl,
    const void* __restrict__ bias, int bFlag,
    float* __restrict__ dst, int mode) {
  __shared__ unsigned short As_hi[64][40];   // [m][k], pad 40 (80B rows)
  __shared__ unsigned short As_lo[64][40];
  __shared__ unsigned short Wt_hi[64][40];   // [n][k]
  __shared__ unsigned short Wt_lo[64][40];
  const int bF = g_flags[bFlag];
  const int tid = threadIdx.x;
  const int m0 = blockIdx.y * 64, n0 = blockIdx.x * 64;
  const int w = tid >> 6, l = tid & 63, c = l & 15, g = l >> 4;
  const int wr = w >> 1, wc = w & 1;
  const int sr = tid >> 2, sc = (tid & 3) * 8;   // staging row / col-chunk

  f32x4 acc[2][2] = {{{0.f, 0.f, 0.f, 0.f}, {0.f, 0.f, 0.f, 0.f}},
                     {{0.f, 0.f, 0.f, 0.f}, {0.f, 0.f, 0.f, 0.f}}};

  for (int k0 = 0; k0 < 512; k0 += 32) {
    __syncthreads();
    {
      const size_t ga = (size_t)(m0 + sr) * 512 + k0 + sc;
      const size_t gw = (size_t)(n0 + sr) * 512 + k0 + sc;
      const bf16x8 ah = *(const bf16x8*)(Ahi + ga);
      const bf16x8 al = *(const bf16x8*)(Alo + ga);
      const bf16x8 wh = *(const bf16x8*)(Wth + gw);
      const bf16x8 wl = *(const bf16x8*)(Wtl + gw);
      *(bf16x8*)&As_hi[sr][sc] = ah;
      *(bf16x8*)&As_lo[sr][sc] = al;
      *(bf16x8*)&Wt_hi[sr][sc] = wh;
      *(bf16x8*)&Wt_lo[sr][sc] = wl;
    }
    __syncthreads();
#pragma unroll
    for (int mi = 0; mi < 2; ++mi) {
      const bf16x8 ah = *(const bf16x8*)&As_hi[wr * 32 + mi * 16 + c][g * 8];
      const bf16x8 al = *(const bf16x8*)&As_lo[wr * 32 + mi * 16 + c][g * 8];
#pragma unroll
      for (int nj = 0; nj < 2; ++nj) {
        const bf16x8 wh = *(const bf16x8*)&Wt_hi[wc * 32 + nj * 16 + c][g * 8];
        const bf16x8 wl = *(const bf16x8*)&Wt_lo[wc * 32 + nj * 16 + c][g * 8];
        acc[mi][nj] = MFMA16(ah, wh, acc[mi][nj]);
        acc[mi][nj] = MFMA16(al, wh, acc[mi][nj]);
        acc[mi][nj] = MFMA16(ah, wl, acc[mi][nj]);
      }
    }
  }
  // epilogue: D[i][j], lane(c,g) reg r -> i = 4g+r (A-row), j = c (W^T-row)
#pragma unroll
  for (int mi = 0; mi < 2; ++mi)
#pragma unroll
    for (int nj = 0; nj < 2; ++nj)
#pragma unroll
      for (int r = 0; r < 4; ++r) {
        const int m = m0 + wr * 32 + mi * 16 + 4 * g + r;
        const int n = n0 + wc * 32 + nj * 16 + c;
        const float v2 = acc[mi][nj][r] + ldf(bias, bF, n);
        if (mode == 3) {
          dst[(size_t)m * 512 + n] = v2;
        } else {
          const int b = m >> 9, s = m & 511, h = n >> 6, d = n & 63;
          const unsigned short hi = f2bf(v2);
          const unsigned short lo = f2bf(v2 - bf2f(hi));
          if (mode == 0) {
            const size_t i0 = (((size_t)(b * nH + h) * nS) + s) * nD + d;
            g_qhi[i0] = hi; g_qlo[i0] = lo;
          } else if (mode == 1) {
            const size_t i0 = (((size_t)(b * nH + h) * nS) + s) * nD + d;
            g_khi[i0] = hi; g_klo[i0] = lo;
          } else {
            const size_t i0 = (((size_t)(b * nH + h) * nD) + d) * nS + s;
            g_vhiT[i0] = hi; g_vloT[i0] = lo;
          }
        }
      }
}

// ---------------- fused MFMA attention: one block per (bh, 16-query tile) ---
// 4 waves; wave w owns keys [w*128, w*128+128). Scores kept transposed
// (S^T = mfma(K, Q^T)) so each lane owns one q-column -> register softmax.
// dist/edge/mask staged to LDS bytes with coalesced int4 loads (no gathers).
__global__ __launch_bounds__(256) void attn_kernel(
    const int* __restrict__ dist, const int* __restrict__ edge,
    const unsigned char* __restrict__ mraw, const unsigned char* __restrict__ fraw,
    const void* __restrict__ vhe, const void* __restrict__ vee) {
  __shared__ float chop_s[16][33];
  __shared__ float cedge_s[16][17];
  __shared__ float vha_s[16][33];
  __shared__ float vea_s[16][17];
  __shared__ float red_s[16][4];
  __shared__ float red2_s[16][4];
  __shared__ float rinv_s[16];
  __shared__ float x_s[64][17];              // out^T partial-sum [d][q]
  __shared__ unsigned char dlds[16][516];    // dist bins, stride 516 (bank spread)
  __shared__ unsigned char elds[16][516];    // edge bins
  __shared__ unsigned char flds[16][516];    // focal mask bytes (h>=4)
  __shared__ unsigned char smask_l[516];     // node mask bytes (h<4)

  const int bh = blockIdx.x, qt = blockIdx.y;   // bh fast: 8 heads share dist slice in L2
  const int b = bh >> 3, h = bh & 7;
  const int q0 = qt * 16;
  const int tid = threadIdx.x;
  const int w = tid >> 6, l = tid & 63, c = l & 15, g = l >> 4;

  const int d64 = g_flags[0], e64 = g_flags[1];
  const int mmode = g_flags[2], fmode = g_flags[3];
  const int fvhe = g_flags[11], fvee = g_flags[12];

  // zero accumulators in LDS
  for (int i = tid; i < 16 * 33; i += 256) (&vha_s[0][0])[i] = 0.f;
  for (int i = tid; i < 16 * 17; i += 256) (&vea_s[0][0])[i] = 0.f;
  for (int i = tid; i < 64 * 17; i += 256) (&x_s[0][0])[i] = 0.f;

  // ---- stage dist/edge bins + masks into LDS (coalesced) -------------------
  const size_t rowbase = ((size_t)b * nS + q0) * nS;
  if (!d64) {
    const int4* dp = (const int4*)(dist + rowbase);
    for (int j4 = tid; j4 < 2048; j4 += 256) {
      const int4 t = dp[j4];
      const int j = j4 * 4, r = j >> 9, c1 = j & 511;
      *(unsigned*)&dlds[r][c1] =
          (unsigned)(t.x & 31) | ((unsigned)(t.y & 31) << 8) |
          ((unsigned)(t.z & 31) << 16) | ((unsigned)(t.w & 31) << 24);
    }
  } else {
    const int4* dp = (const int4*)(dist + 2 * rowbase);
    for (int j2 = tid; j2 < 4096; j2 += 256) {
      const int4 t = dp[j2];
      const int j = j2 * 2, r = j >> 9, c1 = j & 511;
      *(unsigned short*)&dlds[r][c1] =
          (unsigned short)((t.x & 31) | ((t.z & 31) << 8));
    }
  }
  if (!e64) {
    const int4* ep = (const int4*)(edge + rowbase);
    for (int j4 = tid; j4 < 2048; j4 += 256) {
      const int4 t = ep[j4];
      const int j = j4 * 4, r = j >> 9, c1 = j & 511;
      *(unsigned*)&elds[r][c1] =
          (unsigned)(t.x & 15) | ((unsigned)(t.y & 15) << 8) |
          ((unsigned)(t.z & 15) << 16) | ((unsigned)(t.w & 15) << 24);
    }
  } else {
    const int4* ep = (const int4*)(edge + 2 * rowbase);
    for (int j2 = tid; j2 < 4096; j2 += 256) {
      const int4 t = ep[j2];
      const int j = j2 * 2, r = j >> 9, c1 = j & 511;
      *(unsigned short*)&elds[r][c1] =
          (unsigned short)((t.x & 15) | ((t.z & 15) << 8));
    }
  }
  if (h < 4) {
    for (int i4 = tid; i4 < 128; i4 += 256) {
      unsigned wv = 0;
#pragma unroll
      for (int t = 0; t < 4; ++t)
        wv |= (unsigned)bool_at(mraw, mmode, (size_t)b * nS + i4 * 4 + t) << (8 * t);
      *(unsigned*)&smask_l[i4 * 4] = wv;
    }
  } else {
    for (int i4 = tid; i4 < 2048; i4 += 256) {
      const int j = i4 * 4, r = j >> 9, c1 = j & 511;
      unsigned wv = 0;
#pragma unroll
      for (int t = 0; t < 4; ++t)
        wv |= (unsigned)bool_at(fraw, fmode, rowbase + j + t) << (8 * t);
      *(unsigned*)&flds[r][c1] = wv;
    }
  }

  // Q fragments for this block's 16 query rows (lane: row=c, d=g*8..+7 [+32])
  const size_t qbase = (((size_t)bh * nS) + q0 + c) * nD + g * 8;
  const bf16x8 qh0 = *(const bf16x8*)(g_qhi + qbase);
  const bf16x8 qh1 = *(const bf16x8*)(g_qhi + qbase + 32);
  const bf16x8 ql0 = *(const bf16x8*)(g_qlo + qbase);
  const bf16x8 ql1 = *(const bf16x8*)(g_qlo + qbase + 32);

  // ---- Phase 0: bias tables via MFMA. waves 0,1: hop t 0-15/16-31; wave 2: edge
  if (w < 3) {
    const bool isEdge = (w == 2);
    const int tb = (w == 1) ? 16 : 0;
    const size_t qe0 = (isEdge ? (size_t)64 * 512 : 0) + (size_t)(tb + c) * 512 + h * 64;
    const size_t ke0 = (isEdge ? (size_t)80 * 512 : (size_t)32 * 512) + (size_t)(tb + c) * 512 + h * 64;
    f32x4 acc = {0.f, 0.f, 0.f, 0.f};
#pragma unroll
    for (int dh = 0; dh < 2; ++dh) {
      const bf16x8 qhh = dh ? qh1 : qh0;
      const bf16x8 qll = dh ? ql1 : ql0;
      const bf16x8 khq = *(const bf16x8*)(g_khi + qbase + dh * 32);
      const bf16x8 klq = *(const bf16x8*)(g_klo + qbase + dh * 32);
      const bf16x8 eqh = *(const bf16x8*)(g_embh + qe0 + dh * 32 + g * 8);
      const bf16x8 eql = *(const bf16x8*)(g_embl + qe0 + dh * 32 + g * 8);
      const bf16x8 ekh = *(const bf16x8*)(g_embh + ke0 + dh * 32 + g * 8);
      const bf16x8 ekl = *(const bf16x8*)(g_embl + ke0 + dh * 32 + g * 8);
      acc = MFMA16(qhh, eqh, acc);
      acc = MFMA16(qll, eqh, acc);
      acc = MFMA16(qhh, eql, acc);
      acc = MFMA16(khq, ekh, acc);
      acc = MFMA16(klq, ekh, acc);
      acc = MFMA16(khq, ekl, acc);
    }
    if (!isEdge) {
#pragma unroll
      for (int r = 0; r < 4; ++r) chop_s[4 * g + r][tb + c] = acc[r];
    } else {
#pragma unroll
      for (int r = 0; r < 4; ++r) cedge_s[4 * g + r][c] = acc[r];
    }
  }
  __syncthreads();   // barrier A

  // ---- Phase A: S^T tiles = mfma(K, Q^T) + staged bias, masked -------------
  f32x4 pS[8];
  const int kbw = w * 128;
#pragma unroll
  for (int kt = 0; kt < 8; ++kt) {
    const int kb = kbw + kt * 16;
    const size_t kbase = (((size_t)bh * nS) + kb + c) * nD + g * 8;
    f32x4 acc = {0.f, 0.f, 0.f, 0.f};
    {
      const bf16x8 kh0 = *(const bf16x8*)(g_khi + kbase);
      const bf16x8 kl0 = *(const bf16x8*)(g_klo + kbase);
      acc = MFMA16(kh0, qh0, acc);
      acc = MFMA16(kl0, qh0, acc);
      acc = MFMA16(kh0, ql0, acc);
      const bf16x8 kh1 = *(const bf16x8*)(g_khi + kbase + 32);
      const bf16x8 kl1 = *(const bf16x8*)(g_klo + kbase + 32);
      acc = MFMA16(kh1, qh1, acc);
      acc = MFMA16(kl1, qh1, acc);
      acc = MFMA16(kh1, ql1, acc);
    }
    const int key0 = kb + 4 * g;
    const unsigned dw = *(const unsigned*)&dlds[c][key0];
    const unsigned ew = *(const unsigned*)&elds[c][key0];
    const unsigned fw = (h < 4) ? *(const unsigned*)&smask_l[key0]
                                : *(const unsigned*)&flds[c][key0];
#pragma unroll
    for (int r = 0; r < 4; ++r) {
      const int dv = (dw >> (8 * r)) & 255;
      const int ev = (ew >> (8 * r)) & 255;
      const float s = (acc[r] + chop_s[c][dv] + cedge_s[c][ev]) * SCALE;
      pS[kt][r] = ((fw >> (8 * r)) & 255) ? s : NEGINF;
    }
  }

  // ---- Phase B: softmax across registers + bin scatter ----------------------
  float mx = NEGINF;
#pragma unroll
  for (int kt = 0; kt < 8; ++kt)
#pragma unroll
    for (int r = 0; r < 4; ++r) mx = fmaxf(mx, pS[kt][r]);
  mx = fmaxf(mx, __shfl_xor(mx, 16));
  mx = fmaxf(mx, __shfl_xor(mx, 32));
  if (l < 16) red_s[c][w] = mx;
  __syncthreads();   // barrier B
  const float M = fmaxf(fmaxf(red_s[c][0], red_s[c][1]),
                        fmaxf(red_s[c][2], red_s[c][3]));
  float sum = 0.f;
#pragma unroll
  for (int kt = 0; kt < 8; ++kt) {
    const int key0 = kbw + kt * 16 + 4 * g;
    const unsigned dw = *(const unsigned*)&dlds[c][key0];
    const unsigned ew = *(const unsigned*)&elds[c][key0];
#pragma unroll
    for (int r = 0; r < 4; ++r) {
      const float pv = __expf(pS[kt][r] - M);
      pS[kt][r] = pv;
      sum += pv;
      atomicAdd(&vha_s[c][(dw >> (8 * r)) & 255], pv);
      atomicAdd(&vea_s[c][(ew >> (8 * r)) & 255], pv);
    }
  }
  sum += __shfl_xor(sum, 16);
  sum += __shfl_xor(sum, 32);
  if (l < 16) red2_s[c][w] = sum;
  // pack P to bf16 pairs: pk[kt][0]=(r1,r0), pk[kt][1]=(r3,r2)
  int pk[8][2];
#pragma unroll
  for (int kt = 0; kt < 8; ++kt) {
    pk[kt][0] = ((int)f2bf(pS[kt][1]) << 16) | (int)f2bf(pS[kt][0]);
    pk[kt][1] = ((int)f2bf(pS[kt][3]) << 16) | (int)f2bf(pS[kt][2]);
  }
  __syncthreads();   // barrier C
  if (w == 0 && l < 16) {
    const float tot = red2_s[c][0] + red2_s[c][1] + red2_s[c][2] + red2_s[c][3];
    rinv_s[c] = 1.0f / tot;
  }

  // ---- Phase C: out^T += V^T @ P^T (per-wave partial over its 128 keys) ----
  f32x4 oacc[4] = {{0.f, 0.f, 0.f, 0.f}, {0.f, 0.f, 0.f, 0.f},
                   {0.f, 0.f, 0.f, 0.f}, {0.f, 0.f, 0.f, 0.f}};
  const int srcA = ((g & 1) * 2) * 16 + c;
  const int srcB = srcA + 16;
  const bool hi2 = (g >> 1) != 0;
#pragma unroll
  for (int ks = 0; ks < 4; ++ks) {
    // build B-fragment of P^T for keys [ks*32, ks*32+32)
    const int t0d0 = __shfl(pk[2 * ks][0], srcA);
    const int t1d0 = __shfl(pk[2 * ks + 1][0], srcA);
    const int t0d1 = __shfl(pk[2 * ks][1], srcA);
    const int t1d1 = __shfl(pk[2 * ks + 1][1], srcA);
    const int t0d0b = __shfl(pk[2 * ks][0], srcB);
    const int t1d0b = __shfl(pk[2 * ks + 1][0], srcB);
    const int t0d1b = __shfl(pk[2 * ks][1], srcB);
    const int t1d1b = __shfl(pk[2 * ks + 1][1], srcB);
    union { int i[4]; bf16x8 v; } bu;
    bu.i[0] = hi2 ? t1d0 : t0d0;
    bu.i[1] = hi2 ? t1d1 : t0d1;
    bu.i[2] = hi2 ? t1d0b : t0d0b;
    bu.i[3] = hi2 ? t1d1b : t0d1b;
    const int kk = w * 128 + ks * 32;
#pragma unroll
    for (int t = 0; t < 4; ++t) {
      const size_t vbase = (((size_t)bh * nD) + t * 16 + c) * nS + kk + g * 8;
      const bf16x8 vh_ = *(const bf16x8*)(g_vhiT + vbase);
      const bf16x8 vl_ = *(const bf16x8*)(g_vloT + vbase);
      oacc[t] = MFMA16(vh_, bu.v, oacc[t]);
      oacc[t] = MFMA16(vl_, bu.v, oacc[t]);
    }
  }
#pragma unroll
  for (int t = 0; t < 4; ++t)
#pragma unroll
    for (int r = 0; r < 4; ++r)
      atomicAdd(&x_s[t * 16 + 4 * g + r][c], oacc[t][r]);
  __syncthreads();   // barrier D

  // ---- Tail: add bin-embedding terms, normalize, store hi/lo bf16 ----------
  {
    const int d = tid & 63, qq = tid >> 6;   // q = qq + 4*j
    float val[4];
#pragma unroll
    for (int j = 0; j < 4; ++j) val[j] = x_s[d][qq + 4 * j];
    for (int t = 0; t < THOP; ++t) {
      const float e = ldf(vhe, fvhe, (size_t)t * nHID + h * 64 + d);
#pragma unroll
      for (int j = 0; j < 4; ++j) val[j] += vha_s[qq + 4 * j][t] * e;
    }
    for (int t = 0; t < TEDGE; ++t) {
      const float e = ldf(vee, fvee, (size_t)t * nHID + h * 64 + d);
#pragma unroll
      for (int j = 0; j < 4; ++j) val[j] += vea_s[qq + 4 * j][t] * e;
    }
#pragma unroll
    for (int j = 0; j < 4; ++j) {
      const int q = qq + 4 * j;
      const float xv = val[j] * rinv_s[q];
      const unsigned short hi = f2bf(xv);
      const size_t i0 = ((size_t)b * nS + q0 + q) * nHID + h * 64 + d;
      g_xhi[i0] = hi;
      g_xlo[i0] = f2bf(xv - bf2f(hi));
    }
  }
}

// ---------------- launcher ----------------
extern "C" void kernel_launch(void* const* d_in, const int* in_sizes, int n_in,
                              void* d_out, int out_size, void* d_ws, size_t ws_size,
                              hipStream_t stream) {
  const void* q   = d_in[0];
  const void* k   = d_in[1];
  const void* v   = d_in[2];
  const void* qhe = d_in[3];
  const void* qee = d_in[4];
  const void* khe = d_in[5];
  const void* kee = d_in[6];
  const void* vhe = d_in[7];
  const void* vee = d_in[8];
  const int* dist = (const int*)d_in[9];
  const int* edge = (const int*)d_in[10];
  const unsigned char* mraw = (const unsigned char*)d_in[11];
  const unsigned char* fraw = (const unsigned char*)d_in[12];
  const void* Wq = d_in[13];
  const void* bq = d_in[14];
  const void* Wk = d_in[15];
  const void* bk = d_in[16];
  const void* Wv = d_in[17];
  const void* bv = d_in[18];
  const void* Wo = d_in[19];
  const void* bo = d_in[20];

  detect_all<<<20, 256, 0, stream>>>(q, k, v, qhe, qee, khe, kee, vhe, vee,
                                     dist, edge, mraw, fraw,
                                     Wq, bq, Wk, bk, Wv, bv, Wo, bo);
  emb_prep<<<4, 256, 0, stream>>>(qhe, khe, qee, kee);
  split_prep<<<dim3(2048, 3), 256, 0, stream>>>(q, k, v);
  wt_prep<<<dim3(64, 4), 256, 0, stream>>>(Wq, Wk, Wv, Wo);

  unsigned short* inhi; hipGetSymbolAddress((void**)&inhi, HIP_SYMBOL(g_inhi));
  unsigned short* inlo; hipGetSymbolAddress((void**)&inlo, HIP_SYMBOL(g_inlo));
  unsigned short* wth;  hipGetSymbolAddress((void**)&wth,  HIP_SYMBOL(g_wth));
  unsigned short* wtl;  hipGetSymbolAddress((void**)&wtl,  HIP_SYMBOL(g_wtl));
  unsigned short* xhi;  hipGetSymbolAddress((void**)&xhi,  HIP_SYMBOL(g_xhi));
  unsigned short* xlo;  hipGetSymbolAddress((void**)&xlo,  HIP_SYMBOL(g_xlo));

  gemm_mfma<<<dim3(8, 64), 256, 0, stream>>>(inhi, inlo, wth, wtl,
                                             bq, 14, nullptr, 0);
  gemm_mfma<<<dim3(8, 64), 256, 0, stream>>>(inhi + 2097152, inlo + 2097152,
                                             wth + 262144, wtl + 262144,
                                             bk, 16, nullptr, 1);
  gemm_mfma<<<dim3(8, 64), 256, 0, stream>>>(inhi + 2 * 2097152, inlo + 2 * 2097152,
                                             wth + 2 * 262144, wtl + 2 * 262144,
                                             bv, 18, nullptr, 2);
  attn_kernel<<<dim3(64, 32), 256, 0, stream>>>(dist, edge, mraw, fraw, vhe, vee);
  gemm_mfma<<<dim3(8, 64), 256, 0, stream>>>(xhi, xlo,
                                             wth + 3 * 262144, wtl + 3 * 262144,
                                             bo, 20, (float*)d_out, 3);
}

// Round 4
// 649.091 us; speedup vs baseline: 1.8584x; 1.0196x over previous
//
#include <hip/hip_runtime.h>

// ---------------- problem constants ----------------
constexpr int nB = 8, nS = 512, nH = 8, nD = 64, nHID = 512;
constexpr int THOP = 32, TEDGE = 16;
constexpr float SCALE = 0.125f;   // 64^-0.5
constexpr float NEGINF = -30000.0f;

typedef __attribute__((ext_vector_type(8))) short bf16x8;   // 8 bf16 = 4 VGPR
typedef __attribute__((ext_vector_type(4))) float f32x4;

#define MFMA16(A, B, C) __builtin_amdgcn_mfma_f32_16x16x32_bf16(A, B, C, 0, 0, 0)

// ---------------- module-scope scratch ----------------
__device__ __align__(16) unsigned short g_qhi[(size_t)nB * nH * nS * nD];  // [bh][s][d]
__device__ __align__(16) unsigned short g_qlo[(size_t)nB * nH * nS * nD];
__device__ __align__(16) unsigned short g_khi[(size_t)nB * nH * nS * nD];
__device__ __align__(16) unsigned short g_klo[(size_t)nB * nH * nS * nD];
__device__ __align__(16) unsigned short g_vhiT[(size_t)nB * nH * nD * nS]; // [bh][d][s]
__device__ __align__(16) unsigned short g_vloT[(size_t)nB * nH * nD * nS];
// hi/lo bf16 split of q/k hop+edge embeddings: qhe@0, khe@32*512, qee@64*512, kee@80*512
__device__ __align__(16) unsigned short g_embh[96 * 512];
__device__ __align__(16) unsigned short g_embl[96 * 512];
// pre-split GEMM inputs: q,k,v flattened [3][2M]
__device__ __align__(16) unsigned short g_inhi[(size_t)3 * 2097152];
__device__ __align__(16) unsigned short g_inlo[(size_t)3 * 2097152];
// pre-transposed+split weights W^T [mat][n][k], mats {Wq,Wk,Wv,Wo}
__device__ __align__(16) unsigned short g_wth[(size_t)4 * 262144];
__device__ __align__(16) unsigned short g_wtl[(size_t)4 * 262144];
// attn output, hi/lo bf16 [b*s][hid]
__device__ __align__(16) unsigned short g_xhi[(size_t)nB * nS * nHID];
__device__ __align__(16) unsigned short g_xlo[(size_t)nB * nS * nHID];
// 0:dist64 1:edge64 2:mmode 3:fmode ; dtype flags (0=bf16,1=fp32):
// 4..20 = q,k,v,qhe,qee,khe,kee,vhe,vee,Wq,bq,Wk,bk,Wv,bv,Wo,bo
__device__ int g_flags[32];

// adaptive scalar load: bf16 or fp32 element i
__device__ __forceinline__ float ldf(const void* p, int isf32, size_t i) {
  if (isf32) return ((const float*)p)[i];
  unsigned int w = (unsigned int)(((const unsigned short*)p)[i]) << 16;
  return __uint_as_float(w);
}
__device__ __forceinline__ float bf2f(unsigned short h) {
  return __uint_as_float((unsigned)h << 16);
}
__device__ __forceinline__ float4 ldf4(const void* p, int isf32, size_t i) {
  if (isf32) return ((const float4*)p)[i >> 2];
  const ushort4 u = ((const ushort4*)p)[i >> 2];
  float4 r;
  r.x = bf2f(u.x); r.y = bf2f(u.y); r.z = bf2f(u.z); r.w = bf2f(u.w);
  return r;
}
__device__ __forceinline__ unsigned short f2bf(float x) {   // RNE
  unsigned u = __float_as_uint(x);
  u += 0x7FFFu + ((u >> 16) & 1u);
  return (unsigned short)(u >> 16);
}

// ---------------- bool-encoding detection ----------------
__device__ int detect_bool_mode(const unsigned char* p) {
  if (p[0] == 0x80 && p[1] == 0x3F) return 2;   // bf16
  if (p[0] == 0x00 && p[1] == 0x3C) return 4;   // fp16
  if (p[0] == 0x00 && p[3] == 0x3F) return 3;   // fp32
  for (int i = 0; i < 64; i += 4)               // u8 vs int32
    if (p[i + 1] | p[i + 2] | p[i + 3]) return 1;
  return 0;                                     // int32
}
__device__ __forceinline__ bool bool_at(const unsigned char* p, int mode, size_t i) {
  switch (mode) {
    case 0: return ((const int*)p)[i] != 0;
    case 1: return p[i] != 0;
    case 3: return ((const float*)p)[i] != 0.f;
    default: return ((const unsigned short*)p)[i] != 0;  // bf16/fp16
  }
}

// -------- parallel detection: one block per array/task, sampled -------------
__global__ __launch_bounds__(256) void detect_all(
    const void* q, const void* k, const void* v,
    const void* qhe, const void* qee, const void* khe, const void* kee,
    const void* vhe, const void* vee,
    const int* dist, const int* edge,
    const unsigned char* mraw, const unsigned char* fraw,
    const void* Wq, const void* bq, const void* Wk, const void* bk,
    const void* Wv, const void* bv, const void* Wo, const void* bo) {
  __shared__ float sred[256];
  __shared__ int nzs;
  const int tid = threadIdx.x;
  const int blk = blockIdx.x;

  if (blk < 17) {
    const void* arrs[17] = {q, k, v, qhe, qee, khe, kee, vhe, vee,
                            Wq, bq, Wk, bk, Wv, bv, Wo, bo};
    const int full[17] = {2097152, 2097152, 2097152, 8192, 8192, 8192, 8192,
                          8192, 8192, 262144, 512, 262144, 512, 262144, 512,
                          262144, 512};
    const int n = full[blk] < 16384 ? full[blk] : 16384;   // sampled scan
    const unsigned short* u = (const unsigned short*)arrs[blk];
    float m = 0.f;
    for (int i = tid; i < n; i += 256) {
      float x = __uint_as_float((unsigned int)u[i] << 16);
      if (x != x) x = 1e20f;
      m = fmaxf(m, fabsf(x));
    }
    sred[tid] = m;
    __syncthreads();
    for (int s = 128; s > 0; s >>= 1) {
      if (tid < s) sred[tid] = fmaxf(sred[tid], sred[tid + s]);
      __syncthreads();
    }
    if (tid == 0) g_flags[4 + blk] = (sred[0] > 1e3f) ? 1 : 0;
  } else if (blk == 17 || blk == 18) {
    const int* p = (blk == 17) ? dist : edge;
    if (tid == 0) nzs = 0;
    __syncthreads();
    int a = 0;
    for (int i = tid; i < 4096; i += 256) a |= p[2 * i + 1];
    if (a) atomicOr(&nzs, 1);
    __syncthreads();
    if (tid == 0) g_flags[blk - 17] = (nzs == 0);   // all-zero high words -> int64
  } else {
    if (tid == 0) {
      g_flags[2] = detect_bool_mode(mraw);
      g_flags[3] = detect_bool_mode(fraw);
    }
  }
}

// -------- emb prep: split q/k hop+edge embeddings into bf16 hi/lo ----------
__global__ __launch_bounds__(256) void emb_prep(
    const void* qhe, const void* khe, const void* qee, const void* kee) {
  const int blk = blockIdx.x;  // 0:qhe 1:khe 2:qee 3:kee
  const void* srcs[4] = {qhe, khe, qee, kee};
  const int flagIdx[4] = {7, 9, 8, 10};
  const int counts[4] = {32 * 512, 32 * 512, 16 * 512, 16 * 512};
  const int dsts[4] = {0, 32 * 512, 64 * 512, 80 * 512};
  const int f = g_flags[flagIdx[blk]];
  const void* src = srcs[blk];
  const int n = counts[blk], d0 = dsts[blk];
  for (int i = threadIdx.x; i < n; i += 256) {
    const float x = ldf(src, f, i);
    const unsigned short hi = f2bf(x);
    g_embh[d0 + i] = hi;
    g_embl[d0 + i] = f2bf(x - bf2f(hi));
  }
}

// -------- split q/k/v inputs into bf16 hi/lo (once) -------------------------
__global__ __launch_bounds__(256) void split_prep(
    const void* q, const void* k, const void* v) {
  const int t = blockIdx.y;
  const void* srcs[3] = {q, k, v};
  const int f = g_flags[4 + t];
  const size_t base = (size_t)t * 2097152;
  const size_t i = ((size_t)blockIdx.x * 256 + threadIdx.x) * 4;
  const float4 v4 = ldf4(srcs[t], f, i);
  ushort4 h4, l4;
  h4.x = f2bf(v4.x); l4.x = f2bf(v4.x - bf2f(h4.x));
  h4.y = f2bf(v4.y); l4.y = f2bf(v4.y - bf2f(h4.y));
  h4.z = f2bf(v4.z); l4.z = f2bf(v4.z - bf2f(h4.z));
  h4.w = f2bf(v4.w); l4.w = f2bf(v4.w - bf2f(h4.w));
  *(ushort4*)&g_inhi[base + i] = h4;
  *(ushort4*)&g_inlo[base + i] = l4;
}

// -------- transpose + split weights: W[k][n] -> W^T[n][k] hi/lo (once) ------
__global__ __launch_bounds__(256) void wt_prep(
    const void* Wq, const void* Wk, const void* Wv, const void* Wo) {
  __shared__ float t[64][65];
  const int mat = blockIdx.y;
  const void* srcs[4] = {Wq, Wk, Wv, Wo};
  const int fIdx[4] = {13, 15, 17, 19};
  const int f = g_flags[fIdx[mat]];
  const void* W = srcs[mat];
  const int k0 = (blockIdx.x >> 3) * 64, n0 = (blockIdx.x & 7) * 64;
  const int tid = threadIdx.x;
  const int r = tid >> 4, c4 = (tid & 15) * 4;
#pragma unroll
  for (int i = 0; i < 4; ++i) {
    const float4 v4 = ldf4(W, f, (size_t)(k0 + r + i * 16) * 512 + n0 + c4);
    t[r + i * 16][c4] = v4.x;
    t[r + i * 16][c4 + 1] = v4.y;
    t[r + i * 16][c4 + 2] = v4.z;
    t[r + i * 16][c4 + 3] = v4.w;
  }
  __syncthreads();
  unsigned short* dh = g_wth + (size_t)mat * 262144;
  unsigned short* dl = g_wtl + (size_t)mat * 262144;
#pragma unroll
  for (int i = 0; i < 4; ++i) {
    const int rn = r + i * 16;
    ushort4 h4, l4;
    const float v0 = t[c4][rn], v1 = t[c4 + 1][rn];
    const float v2 = t[c4 + 2][rn], v3 = t[c4 + 3][rn];
    h4.x = f2bf(v0); l4.x = f2bf(v0 - bf2f(h4.x));
    h4.y = f2bf(v1); l4.y = f2bf(v1 - bf2f(h4.y));
    h4.z = f2bf(v2); l4.z = f2bf(v2 - bf2f(h4.z));
    h4.w = f2bf(v3); l4.w = f2bf(v3 - bf2f(h4.w));
    *(ushort4*)&dh[(size_t)(n0 + rn) * 512 + k0 + c4] = h4;
    *(ushort4*)&dl[(size_t)(n0 + rn) * 512 + k0 + c4] = l4;
  }
}

// -------- MFMA GEMM with register prefetch (2-phase pipeline) ---------------
// 64x64 tile / block, 4 waves each computing a 32x32 sub-tile. K-step 32.
__global__ __launch_bounds__(256) void gemm_mfma(
    const unsigned short* __restrict__ Ahi, const unsigned short* __restrict__ Alo,
    const unsigned short* __restrict__ Wth, const unsigned short* __restrict__ Wtl,
    const void* __restrict__ bias, int bFlag,
    float* __restrict__ dst, int mode) {
  __shared__ unsigned short As_hi[64][40];
  __shared__ unsigned short As_lo[64][40];
  __shared__ unsigned short Wt_hi[64][40];
  __shared__ unsigned short Wt_lo[64][40];
  const int bF = g_flags[bFlag];
  const int tid = threadIdx.x;
  const int m0 = blockIdx.y * 64, n0 = blockIdx.x * 64;
  const int w = tid >> 6, l = tid & 63, c = l & 15, g = l >> 4;
  const int wr = w >> 1, wc = w & 1;
  const int sr = tid >> 2, sc = (tid & 3) * 8;

  f32x4 acc[2][2] = {{{0.f, 0.f, 0.f, 0.f}, {0.f, 0.f, 0.f, 0.f}},
                     {{0.f, 0.f, 0.f, 0.f}, {0.f, 0.f, 0.f, 0.f}}};

  const size_t ga = (size_t)(m0 + sr) * 512 + sc;
  const size_t gw = (size_t)(n0 + sr) * 512 + sc;
  bf16x8 pa_h = *(const bf16x8*)(Ahi + ga);
  bf16x8 pa_l = *(const bf16x8*)(Alo + ga);
  bf16x8 pw_h = *(const bf16x8*)(Wth + gw);
  bf16x8 pw_l = *(const bf16x8*)(Wtl + gw);

  for (int k0 = 0; k0 < 512; k0 += 32) {
    __syncthreads();
    *(bf16x8*)&As_hi[sr][sc] = pa_h;
    *(bf16x8*)&As_lo[sr][sc] = pa_l;
    *(bf16x8*)&Wt_hi[sr][sc] = pw_h;
    *(bf16x8*)&Wt_lo[sr][sc] = pw_l;
    __syncthreads();
    if (k0 < 480) {   // prefetch next K-tile; overlaps with MFMAs below
      pa_h = *(const bf16x8*)(Ahi + ga + k0 + 32);
      pa_l = *(const bf16x8*)(Alo + ga + k0 + 32);
      pw_h = *(const bf16x8*)(Wth + gw + k0 + 32);
      pw_l = *(const bf16x8*)(Wtl + gw + k0 + 32);
    }
#pragma unroll
    for (int mi = 0; mi < 2; ++mi) {
      const bf16x8 ah = *(const bf16x8*)&As_hi[wr * 32 + mi * 16 + c][g * 8];
      const bf16x8 al = *(const bf16x8*)&As_lo[wr * 32 + mi * 16 + c][g * 8];
#pragma unroll
      for (int nj = 0; nj < 2; ++nj) {
        const bf16x8 wh = *(const bf16x8*)&Wt_hi[wc * 32 + nj * 16 + c][g * 8];
        const bf16x8 wl = *(const bf16x8*)&Wt_lo[wc * 32 + nj * 16 + c][g * 8];
        acc[mi][nj] = MFMA16(ah, wh, acc[mi][nj]);
        acc[mi][nj] = MFMA16(al, wh, acc[mi][nj]);
        acc[mi][nj] = MFMA16(ah, wl, acc[mi][nj]);
      }
    }
  }
#pragma unroll
  for (int mi = 0; mi < 2; ++mi)
#pragma unroll
    for (int nj = 0; nj < 2; ++nj)
#pragma unroll
      for (int r = 0; r < 4; ++r) {
        const int m = m0 + wr * 32 + mi * 16 + 4 * g + r;
        const int n = n0 + wc * 32 + nj * 16 + c;
        const float v2 = acc[mi][nj][r] + ldf(bias, bF, n);
        if (mode == 3) {
          dst[(size_t)m * 512 + n] = v2;
        } else {
          const int b = m >> 9, s = m & 511, h = n >> 6, d = n & 63;
          const unsigned short hi = f2bf(v2);
          const unsigned short lo = f2bf(v2 - bf2f(hi));
          if (mode == 0) {
            const size_t i0 = (((size_t)(b * nH + h) * nS) + s) * nD + d;
            g_qhi[i0] = hi; g_qlo[i0] = lo;
          } else if (mode == 1) {
            const size_t i0 = (((size_t)(b * nH + h) * nS) + s) * nD + d;
            g_khi[i0] = hi; g_klo[i0] = lo;
          } else {
            const size_t i0 = (((size_t)(b * nH + h) * nD) + d) * nS + s;
            g_vhiT[i0] = hi; g_vloT[i0] = lo;
          }
        }
      }
}

// ---------------- fused MFMA attention ---------------------------------------
// One block per (bh, 16-query tile), 4 waves. Scores transposed (S^T=mfma(K,Q^T))
// -> register softmax. K staged to LDS in 64-key chunks (hi+lo, XOR-swizzled,
// cooperative coalesced loads); V-hi staged in 128-key chunks (same buffer),
// V-lo direct from global. dist/edge/keep packed to one u16 LDS array.
__global__ __launch_bounds__(256) void attn_kernel(
    const int* __restrict__ dist, const int* __restrict__ edge,
    const unsigned char* __restrict__ mraw, const unsigned char* __restrict__ fraw,
    const void* __restrict__ vhe, const void* __restrict__ vee) {
  __shared__ unsigned short kvbuf[8192];    // K: hi@[0,4096) lo@[4096,8192); V-hi: [0,8192)
  __shared__ unsigned short plds[16][520];  // d | e<<5 | keep<<9 ; overlaid by x_s later
  __shared__ float chop_s[16][33];
  __shared__ float cedge_s[16][17];
  __shared__ float vha_s[16][33];
  __shared__ float vea_s[16][17];
  __shared__ float red_s[16][4];
  __shared__ float red2_s[16][4];
  __shared__ float rinv_s[16];

  // XCD-aware swizzle: 8 consecutive slots per XCD share batch b -> L2 locality
  const int id = blockIdx.x;
  const int bh = (id & 7) * 8 + ((id >> 3) & 7);
  const int qt = id >> 6;
  const int b = bh >> 3, h = bh & 7;
  const int q0 = qt * 16;
  const int tid = threadIdx.x;
  const int w = tid >> 6, l = tid & 63, c = l & 15, g = l >> 4;

  const int d64 = g_flags[0], e64 = g_flags[1];
  const int mmode = g_flags[2], fmode = g_flags[3];
  const int fvhe = g_flags[11], fvee = g_flags[12];

  for (int i = tid; i < 16 * 33; i += 256) (&vha_s[0][0])[i] = 0.f;
  for (int i = tid; i < 16 * 17; i += 256) (&vea_s[0][0])[i] = 0.f;

  // ---- stage packed (dist,edge,keep) metadata, coalesced -------------------
  const size_t rowbase = ((size_t)b * nS + q0) * nS;
  for (int j4 = tid; j4 < 2048; j4 += 256) {
    const int j = j4 * 4, r = j >> 9, c1 = j & 511;
    int dv[4], ev[4];
    if (!d64) {
      const int4 t = ((const int4*)(dist + rowbase))[j4];
      dv[0] = t.x & 31; dv[1] = t.y & 31; dv[2] = t.z & 31; dv[3] = t.w & 31;
    } else {
      const int4 t0 = ((const int4*)(dist + 2 * rowbase))[2 * j4];
      const int4 t1 = ((const int4*)(dist + 2 * rowbase))[2 * j4 + 1];
      dv[0] = t0.x & 31; dv[1] = t0.z & 31; dv[2] = t1.x & 31; dv[3] = t1.z & 31;
    }
    if (!e64) {
      const int4 t = ((const int4*)(edge + rowbase))[j4];
      ev[0] = t.x & 15; ev[1] = t.y & 15; ev[2] = t.z & 15; ev[3] = t.w & 15;
    } else {
      const int4 t0 = ((const int4*)(edge + 2 * rowbase))[2 * j4];
      const int4 t1 = ((const int4*)(edge + 2 * rowbase))[2 * j4 + 1];
      ev[0] = t0.x & 15; ev[1] = t0.z & 15; ev[2] = t1.x & 15; ev[3] = t1.z & 15;
    }
    ushort4 pw;
    unsigned short* pp = (unsigned short*)&pw;
#pragma unroll
    for (int t = 0; t < 4; ++t) {
      const bool keep = (h < 4) ? bool_at(mraw, mmode, (size_t)b * nS + c1 + t)
                                : bool_at(fraw, fmode, rowbase + j + t);
      pp[t] = (unsigned short)(dv[t] | (ev[t] << 5) | ((int)keep << 9));
    }
    *(ushort4*)&plds[r][c1] = pw;
  }

  // Q fragments (lane: q-row=c, d=g*8..+7 [+32])
  const size_t qbase = (((size_t)bh * nS) + q0 + c) * nD + g * 8;
  const bf16x8 qh0 = *(const bf16x8*)(g_qhi + qbase);
  const bf16x8 qh1 = *(const bf16x8*)(g_qhi + qbase + 32);
  const bf16x8 ql0 = *(const bf16x8*)(g_qlo + qbase);
  const bf16x8 ql1 = *(const bf16x8*)(g_qlo + qbase + 32);

  // ---- Phase 0: bias tables via MFMA. waves 0,1: hop t 0-15/16-31; wave 2: edge
  if (w < 3) {
    const bool isEdge = (w == 2);
    const int tb = (w == 1) ? 16 : 0;
    const size_t qe0 = (isEdge ? (size_t)64 * 512 : 0) + (size_t)(tb + c) * 512 + h * 64;
    const size_t ke0 = (isEdge ? (size_t)80 * 512 : (size_t)32 * 512) + (size_t)(tb + c) * 512 + h * 64;
    f32x4 acc = {0.f, 0.f, 0.f, 0.f};
#pragma unroll
    for (int dh = 0; dh < 2; ++dh) {
      const bf16x8 qhh = dh ? qh1 : qh0;
      const bf16x8 qll = dh ? ql1 : ql0;
      const bf16x8 khq = *(const bf16x8*)(g_khi + qbase + dh * 32);
      const bf16x8 klq = *(const bf16x8*)(g_klo + qbase + dh * 32);
      const bf16x8 eqh = *(const bf16x8*)(g_embh + qe0 + dh * 32 + g * 8);
      const bf16x8 eql = *(const bf16x8*)(g_embl + qe0 + dh * 32 + g * 8);
      const bf16x8 ekh = *(const bf16x8*)(g_embh + ke0 + dh * 32 + g * 8);
      const bf16x8 ekl = *(const bf16x8*)(g_embl + ke0 + dh * 32 + g * 8);
      acc = MFMA16(qhh, eqh, acc);
      acc = MFMA16(qll, eqh, acc);
      acc = MFMA16(qhh, eql, acc);
      acc = MFMA16(khq, ekh, acc);
      acc = MFMA16(klq, ekh, acc);
      acc = MFMA16(khq, ekl, acc);
    }
    if (!isEdge) {
#pragma unroll
      for (int r = 0; r < 4; ++r) chop_s[4 * g + r][tb + c] = acc[r];
    } else {
#pragma unroll
      for (int r = 0; r < 4; ++r) cedge_s[4 * g + r][c] = acc[r];
    }
  }

  // ---- stage K chunk 0 (64 keys x 64 d, hi+lo, XOR-swizzled) ---------------
#pragma unroll
  for (int it = 0; it < 2; ++it) {
    const int e = (tid << 3) + (it << 11);
    const int r = e >> 6, d0 = e & 63;
    const size_t src = (((size_t)bh * nS) + r) * nD + d0;
    const int dsti = (r << 6) + ((((d0 >> 3) ^ (r & 7))) << 3);
    *(bf16x8*)&kvbuf[dsti] = *(const bf16x8*)(g_khi + src);
    *(bf16x8*)&kvbuf[4096 + dsti] = *(const bf16x8*)(g_klo + src);
  }
  __syncthreads();   // barrier A

  // ---- Phase A: S^T tiles from LDS K chunks --------------------------------
  f32x4 pS[8];
  const int sw8 = c & 7;
  for (int ch = 0; ch < 8; ++ch) {
    const int rloc = w * 16 + c;
    const int a0 = rloc << 6;
    f32x4 acc = {0.f, 0.f, 0.f, 0.f};
    {
      const int o0 = a0 + ((g ^ sw8) << 3);
      const int o1 = a0 + ((((4 + g) ^ sw8)) << 3);
      const bf16x8 kh0 = *(const bf16x8*)&kvbuf[o0];
      const bf16x8 kl0 = *(const bf16x8*)&kvbuf[4096 + o0];
      const bf16x8 kh1 = *(const bf16x8*)&kvbuf[o1];
      const bf16x8 kl1 = *(const bf16x8*)&kvbuf[4096 + o1];
      acc = MFMA16(kh0, qh0, acc);
      acc = MFMA16(kl0, qh0, acc);
      acc = MFMA16(kh0, ql0, acc);
      acc = MFMA16(kh1, qh1, acc);
      acc = MFMA16(kl1, qh1, acc);
      acc = MFMA16(kh1, ql1, acc);
    }
    const int key0 = ch * 64 + w * 16 + 4 * g;
    const ushort4 pv4 = *(const ushort4*)&plds[c][key0];
    const unsigned short pp[4] = {pv4.x, pv4.y, pv4.z, pv4.w};
#pragma unroll
    for (int r = 0; r < 4; ++r) {
      const float s = (acc[r] + chop_s[c][pp[r] & 31] +
                       cedge_s[c][(pp[r] >> 5) & 15]) * SCALE;
      pS[ch][r] = (pp[r] & 512) ? s : NEGINF;
    }
    __syncthreads();   // K chunk consumed
    if (ch < 7) {
#pragma unroll
      for (int it = 0; it < 2; ++it) {
        const int e = (tid << 3) + (it << 11);
        const int r = e >> 6, d0 = e & 63;
        const size_t src = (((size_t)bh * nS) + (ch + 1) * 64 + r) * nD + d0;
        const int dsti = (r << 6) + ((((d0 >> 3) ^ (r & 7))) << 3);
        *(bf16x8*)&kvbuf[dsti] = *(const bf16x8*)(g_khi + src);
        *(bf16x8*)&kvbuf[4096 + dsti] = *(const bf16x8*)(g_klo + src);
      }
      __syncthreads();
    }
  }

  // ---- Phase B: softmax across registers + bin scatter ---------------------
  float mx = NEGINF;
#pragma unroll
  for (int kt = 0; kt < 8; ++kt)
#pragma unroll
    for (int r = 0; r < 4; ++r) mx = fmaxf(mx, pS[kt][r]);
  mx = fmaxf(mx, __shfl_xor(mx, 16));
  mx = fmaxf(mx, __shfl_xor(mx, 32));
  if (l < 16) red_s[c][w] = mx;
  __syncthreads();   // barrier B
  const float M = fmaxf(fmaxf(red_s[c][0], red_s[c][1]),
                        fmaxf(red_s[c][2], red_s[c][3]));
  float sum = 0.f;
#pragma unroll
  for (int kt = 0; kt < 8; ++kt) {
    const int key0 = kt * 64 + w * 16 + 4 * g;
    const ushort4 pv4 = *(const ushort4*)&plds[c][key0];
    const unsigned short pp[4] = {pv4.x, pv4.y, pv4.z, pv4.w};
#pragma unroll
    for (int r = 0; r < 4; ++r) {
      const float pv = __expf(pS[kt][r] - M);
      pS[kt][r] = pv;
      sum += pv;
      atomicAdd(&vha_s[c][pp[r] & 31], pv);
      atomicAdd(&vea_s[c][(pp[r] >> 5) & 15], pv);
    }
  }
  sum += __shfl_xor(sum, 16);
  sum += __shfl_xor(sum, 32);
  if (l < 16) red2_s[c][w] = sum;
  // pack P to bf16 pairs
  int pk[8][2];
#pragma unroll
  for (int kt = 0; kt < 8; ++kt) {
    pk[kt][0] = ((int)f2bf(pS[kt][1]) << 16) | (int)f2bf(pS[kt][0]);
    pk[kt][1] = ((int)f2bf(pS[kt][3]) << 16) | (int)f2bf(pS[kt][2]);
  }
  __syncthreads();   // barrier C: plds dead from here
  float (*x_s)[17] = reinterpret_cast<float(*)[17]>(&plds[0][0]);  // overlay
  for (int i = tid; i < 64 * 17; i += 256) (&x_s[0][0])[i] = 0.f;
  if (w == 0 && l < 16) {
    const float tot = red2_s[c][0] + red2_s[c][1] + red2_s[c][2] + red2_s[c][3];
    rinv_s[c] = 1.0f / tot;
  }
  __syncthreads();   // barrier C2

  // ---- Phase C: out^T += V^T @ P^T. V-hi from LDS chunks, V-lo global ------
  f32x4 oacc[4] = {{0.f, 0.f, 0.f, 0.f}, {0.f, 0.f, 0.f, 0.f},
                   {0.f, 0.f, 0.f, 0.f}, {0.f, 0.f, 0.f, 0.f}};
  const int srcA = ((g & 1) * 2) * 16 + c;
  const int srcB = srcA + 16;
  const bool hi2 = (g >> 1) != 0;
  for (int p = 0; p < 4; ++p) {
    // stage V-hi chunk: [64 d][128 keys], XOR-swizzled
#pragma unroll
    for (int it = 0; it < 4; ++it) {
      const int e = (tid << 3) + (it << 11);
      const int d = e >> 7, colc = e & 127;
      const size_t src = (((size_t)bh * nD) + d) * nS + (p << 7) + colc;
      const int dsti = (d << 7) + ((((colc >> 3) ^ (d & 15))) << 3);
      *(bf16x8*)&kvbuf[dsti] = *(const bf16x8*)(g_vhiT + src);
    }
    __syncthreads();
    // build B-fragment of P^T for this 32-key step
    const int t0d0 = __shfl(pk[2 * p][0], srcA);
    const int t1d0 = __shfl(pk[2 * p + 1][0], srcA);
    const int t0d1 = __shfl(pk[2 * p][1], srcA);
    const int t1d1 = __shfl(pk[2 * p + 1][1], srcA);
    const int t0d0b = __shfl(pk[2 * p][0], srcB);
    const int t1d0b = __shfl(pk[2 * p + 1][0], srcB);
    const int t0d1b = __shfl(pk[2 * p][1], srcB);
    const int t1d1b = __shfl(pk[2 * p + 1][1], srcB);
    union { int i[4]; bf16x8 v; } bu;
    bu.i[0] = hi2 ? t1d0 : t0d0;
    bu.i[1] = hi2 ? t1d1 : t0d1;
    bu.i[2] = hi2 ? t1d0b : t0d0b;
    bu.i[3] = hi2 ? t1d1b : t0d1b;
    // k-idx g*8+j <-> key p*128 + (g>>1)*64 + w*16 + (g&1)*8 + j
    const int col16 = (w << 1) + (g & 1) + ((g >> 1) << 3);
    const int j0 = (p << 7) + ((g >> 1) << 6) + (w << 4) + ((g & 1) << 3);
#pragma unroll
    for (int t = 0; t < 4; ++t) {
      const int row = t * 16 + c;
      const bf16x8 vh_ = *(const bf16x8*)&kvbuf[(row << 7) + (((col16 ^ c)) << 3)];
      const bf16x8 vl_ = *(const bf16x8*)(g_vloT + (((size_t)bh * nD) + row) * nS + j0);
      oacc[t] = MFMA16(vh_, bu.v, oacc[t]);
      oacc[t] = MFMA16(vl_, bu.v, oacc[t]);
    }
    __syncthreads();   // V chunk consumed
  }
#pragma unroll
  for (int t = 0; t < 4; ++t)
#pragma unroll
    for (int r = 0; r < 4; ++r)
      atomicAdd(&x_s[t * 16 + 4 * g + r][c], oacc[t][r]);
  __syncthreads();   // barrier D

  // ---- Tail: add bin-embedding terms, normalize, store hi/lo bf16 ----------
  {
    const int d = tid & 63, qq = tid >> 6;
    float val[4];
#pragma unroll
    for (int j = 0; j < 4; ++j) val[j] = x_s[d][qq + 4 * j];
    for (int t = 0; t < THOP; ++t) {
      const float e = ldf(vhe, fvhe, (size_t)t * nHID + h * 64 + d);
#pragma unroll
      for (int j = 0; j < 4; ++j) val[j] += vha_s[qq + 4 * j][t] * e;
    }
    for (int t = 0; t < TEDGE; ++t) {
      const float e = ldf(vee, fvee, (size_t)t * nHID + h * 64 + d);
#pragma unroll
      for (int j = 0; j < 4; ++j) val[j] += vea_s[qq + 4 * j][t] * e;
    }
#pragma unroll
    for (int j = 0; j < 4; ++j) {
      const int q = qq + 4 * j;
      const float xv = val[j] * rinv_s[q];
      const unsigned short hi = f2bf(xv);
      const size_t i0 = ((size_t)b * nS + q0 + q) * nHID + h * 64 + d;
      g_xhi[i0] = hi;
      g_xlo[i0] = f2bf(xv - bf2f(hi));
    }
  }
}

// ---------------- launcher ----------------
extern "C" void kernel_launch(void* const* d_in, const int* in_sizes, int n_in,
                              void* d_out, int out_size, void* d_ws, size_t ws_size,
                              hipStream_t stream) {
  const void* q   = d_in[0];
  const void* k   = d_in[1];
  const void* v   = d_in[2];
  const void* qhe = d_in[3];
  const void* qee = d_in[4];
  const void* khe = d_in[5];
  const void* kee = d_in[6];
  const void* vhe = d_in[7];
  const void* vee = d_in[8];
  const int* dist = (const int*)d_in[9];
  const int* edge = (const int*)d_in[10];
  const unsigned char* mraw = (const unsigned char*)d_in[11];
  const unsigned char* fraw = (const unsigned char*)d_in[12];
  const void* Wq = d_in[13];
  const void* bq = d_in[14];
  const void* Wk = d_in[15];
  const void* bk = d_in[16];
  const void* Wv = d_in[17];
  const void* bv = d_in[18];
  const void* Wo = d_in[19];
  const void* bo = d_in[20];

  detect_all<<<20, 256, 0, stream>>>(q, k, v, qhe, qee, khe, kee, vhe, vee,
                                     dist, edge, mraw, fraw,
                                     Wq, bq, Wk, bk, Wv, bv, Wo, bo);
  emb_prep<<<4, 256, 0, stream>>>(qhe, khe, qee, kee);
  split_prep<<<dim3(2048, 3), 256, 0, stream>>>(q, k, v);
  wt_prep<<<dim3(64, 4), 256, 0, stream>>>(Wq, Wk, Wv, Wo);

  unsigned short* inhi; hipGetSymbolAddress((void**)&inhi, HIP_SYMBOL(g_inhi));
  unsigned short* inlo; hipGetSymbolAddress((void**)&inlo, HIP_SYMBOL(g_inlo));
  unsigned short* wth;  hipGetSymbolAddress((void**)&wth,  HIP_SYMBOL(g_wth));
  unsigned short* wtl;  hipGetSymbolAddress((void**)&wtl,  HIP_SYMBOL(g_wtl));
  unsigned short* xhi;  hipGetSymbolAddress((void**)&xhi,  HIP_SYMBOL(g_xhi));
  unsigned short* xlo;  hipGetSymbolAddress((void**)&xlo,  HIP_SYMBOL(g_xlo));

  gemm_mfma<<<dim3(8, 64), 256, 0, stream>>>(inhi, inlo, wth, wtl,
                                             bq, 14, nullptr, 0);
  gemm_mfma<<<dim3(8, 64), 256, 0, stream>>>(inhi + 2097152, inlo + 2097152,
                                             wth + 262144, wtl + 262144,
                                             bk, 16, nullptr, 1);
  gemm_mfma<<<dim3(8, 64), 256, 0, stream>>>(inhi + 2 * 2097152, inlo + 2 * 2097152,
                                             wth + 2 * 262144, wtl + 2 * 262144,
                                             bv, 18, nullptr, 2);
  attn_kernel<<<2048, 256, 0, stream>>>(dist, edge, mraw, fraw, vhe, vee);
  gemm_mfma<<<dim3(8, 64), 256, 0, stream>>>(xhi, xlo,
                                             wth + 3 * 262144, wtl + 3 * 262144,
                                             bo, 20, (float*)d_out, 3);
}

// Round 5
// 555.130 us; speedup vs baseline: 2.1730x; 1.1693x over previous
//
#include <hip/hip_runtime.h>

// ---------------- problem constants ----------------
constexpr int nB = 8, nS = 512, nH = 8, nD = 64, nHID = 512;
constexpr int THOP = 32, TEDGE = 16;
constexpr float SCALE = 0.125f;   // 64^-0.5
constexpr float NEGINF = -30000.0f;

typedef __attribute__((ext_vector_type(8))) short bf16x8;   // 8 bf16 = 4 VGPR
typedef __attribute__((ext_vector_type(4))) float f32x4;

#define MFMA16(A, B, C) __builtin_amdgcn_mfma_f32_16x16x32_bf16(A, B, C, 0, 0, 0)

// ---------------- module-scope scratch ----------------
__device__ __align__(16) unsigned short g_qhi[(size_t)nB * nH * nS * nD];  // [bh][s][d]
__device__ __align__(16) unsigned short g_qlo[(size_t)nB * nH * nS * nD];
__device__ __align__(16) unsigned short g_khi[(size_t)nB * nH * nS * nD];
__device__ __align__(16) unsigned short g_klo[(size_t)nB * nH * nS * nD];
__device__ __align__(16) unsigned short g_vhiT[(size_t)nB * nH * nD * nS]; // [bh][d][s]
__device__ __align__(16) unsigned short g_vloT[(size_t)nB * nH * nD * nS];
// hi/lo bf16 split of q/k hop+edge embeddings: qhe@0, khe@32*512, qee@64*512, kee@80*512
__device__ __align__(16) unsigned short g_embh[96 * 512];
__device__ __align__(16) unsigned short g_embl[96 * 512];
// pre-split GEMM inputs: q,k,v flattened [3][2M]
__device__ __align__(16) unsigned short g_inhi[(size_t)3 * 2097152];
__device__ __align__(16) unsigned short g_inlo[(size_t)3 * 2097152];
// pre-transposed+split weights W^T [mat][n][k], mats {Wq,Wk,Wv,Wo}
__device__ __align__(16) unsigned short g_wth[(size_t)4 * 262144];
__device__ __align__(16) unsigned short g_wtl[(size_t)4 * 262144];
// attn output, hi/lo bf16 [b*s][hid]
__device__ __align__(16) unsigned short g_xhi[(size_t)nB * nS * nHID];
__device__ __align__(16) unsigned short g_xlo[(size_t)nB * nS * nHID];
// 0:dist64 1:edge64 2:mmode 3:fmode ; dtype flags (0=bf16,1=fp32):
// 4..20 = q,k,v,qhe,qee,khe,kee,vhe,vee,Wq,bq,Wk,bk,Wv,bv,Wo,bo
__device__ int g_flags[32];

// adaptive scalar load: bf16 or fp32 element i
__device__ __forceinline__ float ldf(const void* p, int isf32, size_t i) {
  if (isf32) return ((const float*)p)[i];
  unsigned int w = (unsigned int)(((const unsigned short*)p)[i]) << 16;
  return __uint_as_float(w);
}
__device__ __forceinline__ float bf2f(unsigned short h) {
  return __uint_as_float((unsigned)h << 16);
}
__device__ __forceinline__ float4 ldf4(const void* p, int isf32, size_t i) {
  if (isf32) return ((const float4*)p)[i >> 2];
  const ushort4 u = ((const ushort4*)p)[i >> 2];
  float4 r;
  r.x = bf2f(u.x); r.y = bf2f(u.y); r.z = bf2f(u.z); r.w = bf2f(u.w);
  return r;
}
__device__ __forceinline__ unsigned short f2bf(float x) {   // RNE
  unsigned u = __float_as_uint(x);
  u += 0x7FFFu + ((u >> 16) & 1u);
  return (unsigned short)(u >> 16);
}

// ---------------- bool-encoding detection ----------------
__device__ int detect_bool_mode(const unsigned char* p) {
  if (p[0] == 0x80 && p[1] == 0x3F) return 2;   // bf16
  if (p[0] == 0x00 && p[1] == 0x3C) return 4;   // fp16
  if (p[0] == 0x00 && p[3] == 0x3F) return 3;   // fp32
  for (int i = 0; i < 64; i += 4)               // u8 vs int32
    if (p[i + 1] | p[i + 2] | p[i + 3]) return 1;
  return 0;                                     // int32
}
__device__ __forceinline__ bool bool_at(const unsigned char* p, int mode, size_t i) {
  switch (mode) {
    case 0: return ((const int*)p)[i] != 0;
    case 1: return p[i] != 0;
    case 3: return ((const float*)p)[i] != 0.f;
    default: return ((const unsigned short*)p)[i] != 0;  // bf16/fp16
  }
}

// -------- parallel detection: one block per array/task, sampled -------------
__global__ __launch_bounds__(256) void detect_all(
    const void* q, const void* k, const void* v,
    const void* qhe, const void* qee, const void* khe, const void* kee,
    const void* vhe, const void* vee,
    const int* dist, const int* edge,
    const unsigned char* mraw, const unsigned char* fraw,
    const void* Wq, const void* bq, const void* Wk, const void* bk,
    const void* Wv, const void* bv, const void* Wo, const void* bo) {
  __shared__ float sred[256];
  __shared__ int nzs;
  const int tid = threadIdx.x;
  const int blk = blockIdx.x;

  if (blk < 17) {
    const void* arrs[17] = {q, k, v, qhe, qee, khe, kee, vhe, vee,
                            Wq, bq, Wk, bk, Wv, bv, Wo, bo};
    const int full[17] = {2097152, 2097152, 2097152, 8192, 8192, 8192, 8192,
                          8192, 8192, 262144, 512, 262144, 512, 262144, 512,
                          262144, 512};
    const int n = full[blk] < 16384 ? full[blk] : 16384;   // sampled scan
    const unsigned short* u = (const unsigned short*)arrs[blk];
    float m = 0.f;
    for (int i = tid; i < n; i += 256) {
      float x = __uint_as_float((unsigned int)u[i] << 16);
      if (x != x) x = 1e20f;
      m = fmaxf(m, fabsf(x));
    }
    sred[tid] = m;
    __syncthreads();
    for (int s = 128; s > 0; s >>= 1) {
      if (tid < s) sred[tid] = fmaxf(sred[tid], sred[tid + s]);
      __syncthreads();
    }
    if (tid == 0) g_flags[4 + blk] = (sred[0] > 1e3f) ? 1 : 0;
  } else if (blk == 17 || blk == 18) {
    const int* p = (blk == 17) ? dist : edge;
    if (tid == 0) nzs = 0;
    __syncthreads();
    int a = 0;
    for (int i = tid; i < 4096; i += 256) a |= p[2 * i + 1];
    if (a) atomicOr(&nzs, 1);
    __syncthreads();
    if (tid == 0) g_flags[blk - 17] = (nzs == 0);   // all-zero high words -> int64
  } else {
    if (tid == 0) {
      g_flags[2] = detect_bool_mode(mraw);
      g_flags[3] = detect_bool_mode(fraw);
    }
  }
}

// -------- emb prep: split q/k hop+edge embeddings into bf16 hi/lo ----------
__global__ __launch_bounds__(256) void emb_prep(
    const void* qhe, const void* khe, const void* qee, const void* kee) {
  const int blk = blockIdx.x;  // 0:qhe 1:khe 2:qee 3:kee
  const void* srcs[4] = {qhe, khe, qee, kee};
  const int flagIdx[4] = {7, 9, 8, 10};
  const int counts[4] = {32 * 512, 32 * 512, 16 * 512, 16 * 512};
  const int dsts[4] = {0, 32 * 512, 64 * 512, 80 * 512};
  const int f = g_flags[flagIdx[blk]];
  const void* src = srcs[blk];
  const int n = counts[blk], d0 = dsts[blk];
  for (int i = threadIdx.x; i < n; i += 256) {
    const float x = ldf(src, f, i);
    const unsigned short hi = f2bf(x);
    g_embh[d0 + i] = hi;
    g_embl[d0 + i] = f2bf(x - bf2f(hi));
  }
}

// -------- split q/k/v inputs into bf16 hi/lo (once) -------------------------
__global__ __launch_bounds__(256) void split_prep(
    const void* q, const void* k, const void* v) {
  const int t = blockIdx.y;
  const void* srcs[3] = {q, k, v};
  const int f = g_flags[4 + t];
  const size_t base = (size_t)t * 2097152;
  const size_t i = ((size_t)blockIdx.x * 256 + threadIdx.x) * 4;
  const float4 v4 = ldf4(srcs[t], f, i);
  ushort4 h4, l4;
  h4.x = f2bf(v4.x); l4.x = f2bf(v4.x - bf2f(h4.x));
  h4.y = f2bf(v4.y); l4.y = f2bf(v4.y - bf2f(h4.y));
  h4.z = f2bf(v4.z); l4.z = f2bf(v4.z - bf2f(h4.z));
  h4.w = f2bf(v4.w); l4.w = f2bf(v4.w - bf2f(h4.w));
  *(ushort4*)&g_inhi[base + i] = h4;
  *(ushort4*)&g_inlo[base + i] = l4;
}

// -------- transpose + split weights: W[k][n] -> W^T[n][k] hi/lo (once) ------
__global__ __launch_bounds__(256) void wt_prep(
    const void* Wq, const void* Wk, const void* Wv, const void* Wo) {
  __shared__ float t[64][65];
  const int mat = blockIdx.y;
  const void* srcs[4] = {Wq, Wk, Wv, Wo};
  const int fIdx[4] = {13, 15, 17, 19};
  const int f = g_flags[fIdx[mat]];
  const void* W = srcs[mat];
  const int k0 = (blockIdx.x >> 3) * 64, n0 = (blockIdx.x & 7) * 64;
  const int tid = threadIdx.x;
  const int r = tid >> 4, c4 = (tid & 15) * 4;
#pragma unroll
  for (int i = 0; i < 4; ++i) {
    const float4 v4 = ldf4(W, f, (size_t)(k0 + r + i * 16) * 512 + n0 + c4);
    t[r + i * 16][c4] = v4.x;
    t[r + i * 16][c4 + 1] = v4.y;
    t[r + i * 16][c4 + 2] = v4.z;
    t[r + i * 16][c4 + 3] = v4.w;
  }
  __syncthreads();
  unsigned short* dh = g_wth + (size_t)mat * 262144;
  unsigned short* dl = g_wtl + (size_t)mat * 262144;
#pragma unroll
  for (int i = 0; i < 4; ++i) {
    const int rn = r + i * 16;
    ushort4 h4, l4;
    const float v0 = t[c4][rn], v1 = t[c4 + 1][rn];
    const float v2 = t[c4 + 2][rn], v3 = t[c4 + 3][rn];
    h4.x = f2bf(v0); l4.x = f2bf(v0 - bf2f(h4.x));
    h4.y = f2bf(v1); l4.y = f2bf(v1 - bf2f(h4.y));
    h4.z = f2bf(v2); l4.z = f2bf(v2 - bf2f(h4.z));
    h4.w = f2bf(v3); l4.w = f2bf(v3 - bf2f(h4.w));
    *(ushort4*)&dh[(size_t)(n0 + rn) * 512 + k0 + c4] = h4;
    *(ushort4*)&dl[(size_t)(n0 + rn) * 512 + k0 + c4] = l4;
  }
}

// -------- MFMA GEMM with register prefetch (2-phase pipeline) ---------------
// 64x64 tile / block, 4 waves each computing a 32x32 sub-tile. K-step 32.
__global__ __launch_bounds__(256, 2) void gemm_mfma(
    const unsigned short* __restrict__ Ahi, const unsigned short* __restrict__ Alo,
    const unsigned short* __restrict__ Wth, const unsigned short* __restrict__ Wtl,
    const void* __restrict__ bias, int bFlag,
    float* __restrict__ dst, int mode) {
  __shared__ unsigned short As_hi[64][40];
  __shared__ unsigned short As_lo[64][40];
  __shared__ unsigned short Wt_hi[64][40];
  __shared__ unsigned short Wt_lo[64][40];
  const int bF = g_flags[bFlag];
  const int tid = threadIdx.x;
  const int m0 = blockIdx.y * 64, n0 = blockIdx.x * 64;
  const int w = tid >> 6, l = tid & 63, c = l & 15, g = l >> 4;
  const int wr = w >> 1, wc = w & 1;
  const int sr = tid >> 2, sc = (tid & 3) * 8;

  f32x4 acc[2][2] = {{{0.f, 0.f, 0.f, 0.f}, {0.f, 0.f, 0.f, 0.f}},
                     {{0.f, 0.f, 0.f, 0.f}, {0.f, 0.f, 0.f, 0.f}}};

  const size_t ga = (size_t)(m0 + sr) * 512 + sc;
  const size_t gw = (size_t)(n0 + sr) * 512 + sc;
  bf16x8 pa_h = *(const bf16x8*)(Ahi + ga);
  bf16x8 pa_l = *(const bf16x8*)(Alo + ga);
  bf16x8 pw_h = *(const bf16x8*)(Wth + gw);
  bf16x8 pw_l = *(const bf16x8*)(Wtl + gw);

  for (int k0 = 0; k0 < 512; k0 += 32) {
    __syncthreads();
    *(bf16x8*)&As_hi[sr][sc] = pa_h;
    *(bf16x8*)&As_lo[sr][sc] = pa_l;
    *(bf16x8*)&Wt_hi[sr][sc] = pw_h;
    *(bf16x8*)&Wt_lo[sr][sc] = pw_l;
    __syncthreads();
    if (k0 < 480) {   // prefetch next K-tile; overlaps with MFMAs below
      pa_h = *(const bf16x8*)(Ahi + ga + k0 + 32);
      pa_l = *(const bf16x8*)(Alo + ga + k0 + 32);
      pw_h = *(const bf16x8*)(Wth + gw + k0 + 32);
      pw_l = *(const bf16x8*)(Wtl + gw + k0 + 32);
    }
#pragma unroll
    for (int mi = 0; mi < 2; ++mi) {
      const bf16x8 ah = *(const bf16x8*)&As_hi[wr * 32 + mi * 16 + c][g * 8];
      const bf16x8 al = *(const bf16x8*)&As_lo[wr * 32 + mi * 16 + c][g * 8];
#pragma unroll
      for (int nj = 0; nj < 2; ++nj) {
        const bf16x8 wh = *(const bf16x8*)&Wt_hi[wc * 32 + nj * 16 + c][g * 8];
        const bf16x8 wl = *(const bf16x8*)&Wt_lo[wc * 32 + nj * 16 + c][g * 8];
        acc[mi][nj] = MFMA16(ah, wh, acc[mi][nj]);
        acc[mi][nj] = MFMA16(al, wh, acc[mi][nj]);
        acc[mi][nj] = MFMA16(ah, wl, acc[mi][nj]);
      }
    }
  }
#pragma unroll
  for (int mi = 0; mi < 2; ++mi)
#pragma unroll
    for (int nj = 0; nj < 2; ++nj)
#pragma unroll
      for (int r = 0; r < 4; ++r) {
        const int m = m0 + wr * 32 + mi * 16 + 4 * g + r;
        const int n = n0 + wc * 32 + nj * 16 + c;
        const float v2 = acc[mi][nj][r] + ldf(bias, bF, n);
        if (mode == 3) {
          dst[(size_t)m * 512 + n] = v2;
        } else {
          const int b = m >> 9, s = m & 511, h = n >> 6, d = n & 63;
          const unsigned short hi = f2bf(v2);
          const unsigned short lo = f2bf(v2 - bf2f(hi));
          if (mode == 0) {
            const size_t i0 = (((size_t)(b * nH + h) * nS) + s) * nD + d;
            g_qhi[i0] = hi; g_qlo[i0] = lo;
          } else if (mode == 1) {
            const size_t i0 = (((size_t)(b * nH + h) * nS) + s) * nD + d;
            g_khi[i0] = hi; g_klo[i0] = lo;
          } else {
            const size_t i0 = (((size_t)(b * nH + h) * nD) + d) * nS + s;
            g_vhiT[i0] = hi; g_vloT[i0] = lo;
          }
        }
      }
}

// ---------------- fused MFMA attention ---------------------------------------
// One block per (bh, 16-query tile), 4 waves. Scores transposed (S^T=mfma(K,Q^T))
// -> register softmax. K and V-hi double-buffered in LDS (one barrier/chunk);
// V-lo direct global. __launch_bounds__(256,2) caps TOTAL regs (VGPR+AGPR
// unified on gfx950) at 256 -> 2 blocks/CU guaranteed (was 1: AGPR overflow).
__global__ __launch_bounds__(256, 2) void attn_kernel(
    const int* __restrict__ dist, const int* __restrict__ edge,
    const unsigned char* __restrict__ mraw, const unsigned char* __restrict__ fraw,
    const void* __restrict__ vhe, const void* __restrict__ vee) {
  __shared__ unsigned short kvbuf[2][8192];  // K: hi@[0,4096) lo@[4096,8192); V-hi: full
  __shared__ unsigned short plds[16][520];   // d | e<<5 | keep<<9 ; overlaid by x_s
  __shared__ float chop_s[16][33];
  __shared__ float cedge_s[16][17];
  __shared__ float vha_s[16][33];
  __shared__ float vea_s[16][17];
  __shared__ float red_s[16][4];
  __shared__ float red2_s[16][4];
  __shared__ float rinv_s[16];

  // XCD-aware swizzle: 8 consecutive slots per XCD share batch b -> L2 locality
  const int id = blockIdx.x;
  const int bh = (id & 7) * 8 + ((id >> 3) & 7);
  const int qt = id >> 6;
  const int b = bh >> 3, h = bh & 7;
  const int q0 = qt * 16;
  const int tid = threadIdx.x;
  const int w = tid >> 6, l = tid & 63, c = l & 15, g = l >> 4;

  const int d64 = g_flags[0], e64 = g_flags[1];
  const int mmode = g_flags[2], fmode = g_flags[3];
  const int fvhe = g_flags[11], fvee = g_flags[12];

  for (int i = tid; i < 16 * 33; i += 256) (&vha_s[0][0])[i] = 0.f;
  for (int i = tid; i < 16 * 17; i += 256) (&vea_s[0][0])[i] = 0.f;

  auto stageK = [&](int ch, int buf) {
#pragma unroll
    for (int it = 0; it < 2; ++it) {
      const int e = (tid << 3) + (it << 11);
      const int r = e >> 6, d0 = e & 63;
      const size_t src = (((size_t)bh * nS) + ch * 64 + r) * nD + d0;
      const int dsti = (r << 6) + (((d0 >> 3) ^ (r & 7)) << 3);
      *(bf16x8*)&kvbuf[buf][dsti] = *(const bf16x8*)(g_khi + src);
      *(bf16x8*)&kvbuf[buf][4096 + dsti] = *(const bf16x8*)(g_klo + src);
    }
  };
  auto stageV = [&](int p, int buf) {
#pragma unroll
    for (int it = 0; it < 4; ++it) {
      const int e = (tid << 3) + (it << 11);
      const int d = e >> 7, colc = e & 127;
      const size_t src = (((size_t)bh * nD) + d) * nS + (p << 7) + colc;
      const int dsti = (d << 7) + (((colc >> 3) ^ (d & 15)) << 3);
      *(bf16x8*)&kvbuf[buf][dsti] = *(const bf16x8*)(g_vhiT + src);
    }
  };

  // ---- stage packed (dist,edge,keep) metadata, coalesced -------------------
  const size_t rowbase = ((size_t)b * nS + q0) * nS;
  for (int j4 = tid; j4 < 2048; j4 += 256) {
    const int j = j4 * 4, r = j >> 9, c1 = j & 511;
    int dv[4], ev[4];
    if (!d64) {
      const int4 t = ((const int4*)(dist + rowbase))[j4];
      dv[0] = t.x & 31; dv[1] = t.y & 31; dv[2] = t.z & 31; dv[3] = t.w & 31;
    } else {
      const int4 t0 = ((const int4*)(dist + 2 * rowbase))[2 * j4];
      const int4 t1 = ((const int4*)(dist + 2 * rowbase))[2 * j4 + 1];
      dv[0] = t0.x & 31; dv[1] = t0.z & 31; dv[2] = t1.x & 31; dv[3] = t1.z & 31;
    }
    if (!e64) {
      const int4 t = ((const int4*)(edge + rowbase))[j4];
      ev[0] = t.x & 15; ev[1] = t.y & 15; ev[2] = t.z & 15; ev[3] = t.w & 15;
    } else {
      const int4 t0 = ((const int4*)(edge + 2 * rowbase))[2 * j4];
      const int4 t1 = ((const int4*)(edge + 2 * rowbase))[2 * j4 + 1];
      ev[0] = t0.x & 15; ev[1] = t0.z & 15; ev[2] = t1.x & 15; ev[3] = t1.z & 15;
    }
    ushort4 pw;
    unsigned short* pp = (unsigned short*)&pw;
#pragma unroll
    for (int t = 0; t < 4; ++t) {
      const bool keep = (h < 4) ? bool_at(mraw, mmode, (size_t)b * nS + c1 + t)
                                : bool_at(fraw, fmode, rowbase + j + t);
      pp[t] = (unsigned short)(dv[t] | (ev[t] << 5) | ((int)keep << 9));
    }
    *(ushort4*)&plds[r][c1] = pw;
  }

  // Q fragments (lane: q-row=c, d=g*8..+7 [+32])
  const size_t qbase = (((size_t)bh * nS) + q0 + c) * nD + g * 8;
  const bf16x8 qh0 = *(const bf16x8*)(g_qhi + qbase);
  const bf16x8 qh1 = *(const bf16x8*)(g_qhi + qbase + 32);
  const bf16x8 ql0 = *(const bf16x8*)(g_qlo + qbase);
  const bf16x8 ql1 = *(const bf16x8*)(g_qlo + qbase + 32);

  // ---- Phase 0: bias tables via MFMA. waves 0,1: hop t 0-15/16-31; wave 2: edge
  if (w < 3) {
    const bool isEdge = (w == 2);
    const int tb = (w == 1) ? 16 : 0;
    const size_t qe0 = (isEdge ? (size_t)64 * 512 : 0) + (size_t)(tb + c) * 512 + h * 64;
    const size_t ke0 = (isEdge ? (size_t)80 * 512 : (size_t)32 * 512) + (size_t)(tb + c) * 512 + h * 64;
    f32x4 acc = {0.f, 0.f, 0.f, 0.f};
#pragma unroll
    for (int dh = 0; dh < 2; ++dh) {
      const bf16x8 qhh = dh ? qh1 : qh0;
      const bf16x8 qll = dh ? ql1 : ql0;
      const bf16x8 khq = *(const bf16x8*)(g_khi + qbase + dh * 32);
      const bf16x8 klq = *(const bf16x8*)(g_klo + qbase + dh * 32);
      const bf16x8 eqh = *(const bf16x8*)(g_embh + qe0 + dh * 32 + g * 8);
      const bf16x8 eql = *(const bf16x8*)(g_embl + qe0 + dh * 32 + g * 8);
      const bf16x8 ekh = *(const bf16x8*)(g_embh + ke0 + dh * 32 + g * 8);
      const bf16x8 ekl = *(const bf16x8*)(g_embl + ke0 + dh * 32 + g * 8);
      acc = MFMA16(qhh, eqh, acc);
      acc = MFMA16(qll, eqh, acc);
      acc = MFMA16(qhh, eql, acc);
      acc = MFMA16(khq, ekh, acc);
      acc = MFMA16(klq, ekh, acc);
      acc = MFMA16(khq, ekl, acc);
    }
    if (!isEdge) {
#pragma unroll
      for (int r = 0; r < 4; ++r) chop_s[4 * g + r][tb + c] = acc[r];
    } else {
#pragma unroll
      for (int r = 0; r < 4; ++r) cedge_s[4 * g + r][c] = acc[r];
    }
  }

  stageK(0, 0);
  __syncthreads();   // barrier A (covers chop/cedge + K chunk 0 + plds)

  // ---- Phase A: S^T tiles from double-buffered LDS K chunks ----------------
  f32x4 pS[8];
  const int sw8 = c & 7;
  for (int ch = 0; ch < 8; ++ch) {
    if (ch < 7) stageK(ch + 1, (ch + 1) & 1);   // prefetch into other buffer
    const unsigned short* kb_ = kvbuf[ch & 1];
    const int a0 = (w * 16 + c) << 6;
    f32x4 acc = {0.f, 0.f, 0.f, 0.f};
    {
      const int o0 = a0 + ((g ^ sw8) << 3);
      const int o1 = a0 + (((4 + g) ^ sw8) << 3);
      const bf16x8 kh0 = *(const bf16x8*)&kb_[o0];
      const bf16x8 kl0 = *(const bf16x8*)&kb_[4096 + o0];
      const bf16x8 kh1 = *(const bf16x8*)&kb_[o1];
      const bf16x8 kl1 = *(const bf16x8*)&kb_[4096 + o1];
      acc = MFMA16(kh0, qh0, acc);
      acc = MFMA16(kl0, qh0, acc);
      acc = MFMA16(kh0, ql0, acc);
      acc = MFMA16(kh1, qh1, acc);
      acc = MFMA16(kl1, qh1, acc);
      acc = MFMA16(kh1, ql1, acc);
    }
    const int key0 = ch * 64 + w * 16 + 4 * g;
    const ushort4 pv4 = *(const ushort4*)&plds[c][key0];
    const unsigned short pp[4] = {pv4.x, pv4.y, pv4.z, pv4.w};
#pragma unroll
    for (int r = 0; r < 4; ++r) {
      const float s = (acc[r] + chop_s[c][pp[r] & 31] +
                       cedge_s[c][(pp[r] >> 5) & 15]) * SCALE;
      pS[ch][r] = (pp[r] & 512) ? s : NEGINF;
    }
    __syncthreads();   // next buffer staged + this buffer consumed
  }

  // ---- Phase B: softmax across registers + bin scatter ---------------------
  float mx = NEGINF;
#pragma unroll
  for (int kt = 0; kt < 8; ++kt)
#pragma unroll
    for (int r = 0; r < 4; ++r) mx = fmaxf(mx, pS[kt][r]);
  mx = fmaxf(mx, __shfl_xor(mx, 16));
  mx = fmaxf(mx, __shfl_xor(mx, 32));
  if (l < 16) red_s[c][w] = mx;
  __syncthreads();   // barrier B
  stageV(0, 0);      // issue V chunk 0 early; latency hides under softmax
  const float M = fmaxf(fmaxf(red_s[c][0], red_s[c][1]),
                        fmaxf(red_s[c][2], red_s[c][3]));
  float sum = 0.f;
#pragma unroll
  for (int kt = 0; kt < 8; ++kt) {
    const int key0 = kt * 64 + w * 16 + 4 * g;
    const ushort4 pv4 = *(const ushort4*)&plds[c][key0];
    const unsigned short pp[4] = {pv4.x, pv4.y, pv4.z, pv4.w};
#pragma unroll
    for (int r = 0; r < 4; ++r) {
      const float pv = __expf(pS[kt][r] - M);
      pS[kt][r] = pv;
      sum += pv;
      atomicAdd(&vha_s[c][pp[r] & 31], pv);
      atomicAdd(&vea_s[c][(pp[r] >> 5) & 15], pv);
    }
  }
  sum += __shfl_xor(sum, 16);
  sum += __shfl_xor(sum, 32);
  if (l < 16) red2_s[c][w] = sum;
  // pack P to bf16 pairs
  int pk[8][2];
#pragma unroll
  for (int kt = 0; kt < 8; ++kt) {
    pk[kt][0] = ((int)f2bf(pS[kt][1]) << 16) | (int)f2bf(pS[kt][0]);
    pk[kt][1] = ((int)f2bf(pS[kt][3]) << 16) | (int)f2bf(pS[kt][2]);
  }
  __syncthreads();   // barrier C: plds dead from here
  float (*x_s)[17] = reinterpret_cast<float(*)[17]>(&plds[0][0]);  // overlay
  for (int i = tid; i < 64 * 17; i += 256) (&x_s[0][0])[i] = 0.f;
  if (w == 0 && l < 16) {
    const float tot = red2_s[c][0] + red2_s[c][1] + red2_s[c][2] + red2_s[c][3];
    rinv_s[c] = 1.0f / tot;
  }
  __syncthreads();   // barrier C2: V chunk 0 staged + x_s zeroed

  // ---- Phase C: out^T += V^T @ P^T, double-buffered V-hi; V-lo global ------
  f32x4 oacc[4] = {{0.f, 0.f, 0.f, 0.f}, {0.f, 0.f, 0.f, 0.f},
                   {0.f, 0.f, 0.f, 0.f}, {0.f, 0.f, 0.f, 0.f}};
  const int srcA = ((g & 1) * 2) * 16 + c;
  const int srcB = srcA + 16;
  const bool hi2 = (g >> 1) != 0;
  for (int p = 0; p < 4; ++p) {
    if (p < 3) stageV(p + 1, (p + 1) & 1);   // prefetch into other buffer
    const unsigned short* vb_ = kvbuf[p & 1];
    // build B-fragment of P^T for this 32-key step
    const int t0d0 = __shfl(pk[2 * p][0], srcA);
    const int t1d0 = __shfl(pk[2 * p + 1][0], srcA);
    const int t0d1 = __shfl(pk[2 * p][1], srcA);
    const int t1d1 = __shfl(pk[2 * p + 1][1], srcA);
    const int t0d0b = __shfl(pk[2 * p][0], srcB);
    const int t1d0b = __shfl(pk[2 * p + 1][0], srcB);
    const int t0d1b = __shfl(pk[2 * p][1], srcB);
    const int t1d1b = __shfl(pk[2 * p + 1][1], srcB);
    union { int i[4]; bf16x8 v; } bu;
    bu.i[0] = hi2 ? t1d0 : t0d0;
    bu.i[1] = hi2 ? t1d1 : t0d1;
    bu.i[2] = hi2 ? t1d0b : t0d0b;
    bu.i[3] = hi2 ? t1d1b : t0d1b;
    // k-idx g*8+j <-> key p*128 + (g>>1)*64 + w*16 + (g&1)*8 + j
    const int col16 = (w << 1) + (g & 1) + ((g >> 1) << 3);
    const int j0 = (p << 7) + ((g >> 1) << 6) + (w << 4) + ((g & 1) << 3);
#pragma unroll
    for (int t = 0; t < 4; ++t) {
      const int row = t * 16 + c;
      const bf16x8 vh_ = *(const bf16x8*)&vb_[(row << 7) + ((col16 ^ c) << 3)];
      const bf16x8 vl_ = *(const bf16x8*)(g_vloT + (((size_t)bh * nD) + row) * nS + j0);
      oacc[t] = MFMA16(vh_, bu.v, oacc[t]);
      oacc[t] = MFMA16(vl_, bu.v, oacc[t]);
    }
    __syncthreads();   // next buffer staged + this buffer consumed
  }
#pragma unroll
  for (int t = 0; t < 4; ++t)
#pragma unroll
    for (int r = 0; r < 4; ++r)
      atomicAdd(&x_s[t * 16 + 4 * g + r][c], oacc[t][r]);
  __syncthreads();   // barrier D

  // ---- Tail: add bin-embedding terms, normalize, store hi/lo bf16 ----------
  {
    const int d = tid & 63, qq = tid >> 6;
    float val[4];
#pragma unroll
    for (int j = 0; j < 4; ++j) val[j] = x_s[d][qq + 4 * j];
    for (int t = 0; t < THOP; ++t) {
      const float e = ldf(vhe, fvhe, (size_t)t * nHID + h * 64 + d);
#pragma unroll
      for (int j = 0; j < 4; ++j) val[j] += vha_s[qq + 4 * j][t] * e;
    }
    for (int t = 0; t < TEDGE; ++t) {
      const float e = ldf(vee, fvee, (size_t)t * nHID + h * 64 + d);
#pragma unroll
      for (int j = 0; j < 4; ++j) val[j] += vea_s[qq + 4 * j][t] * e;
    }
#pragma unroll
    for (int j = 0; j < 4; ++j) {
      const int q = qq + 4 * j;
      const float xv = val[j] * rinv_s[q];
      const unsigned short hi = f2bf(xv);
      const size_t i0 = ((size_t)b * nS + q0 + q) * nHID + h * 64 + d;
      g_xhi[i0] = hi;
      g_xlo[i0] = f2bf(xv - bf2f(hi));
    }
  }
}

// ---------------- launcher ----------------
extern "C" void kernel_launch(void* const* d_in, const int* in_sizes, int n_in,
                              void* d_out, int out_size, void* d_ws, size_t ws_size,
                              hipStream_t stream) {
  const void* q   = d_in[0];
  const void* k   = d_in[1];
  const void* v   = d_in[2];
  const void* qhe = d_in[3];
  const void* qee = d_in[4];
  const void* khe = d_in[5];
  const void* kee = d_in[6];
  const void* vhe = d_in[7];
  const void* vee = d_in[8];
  const int* dist = (const int*)d_in[9];
  const int* edge = (const int*)d_in[10];
  const unsigned char* mraw = (const unsigned char*)d_in[11];
  const unsigned char* fraw = (const unsigned char*)d_in[12];
  const void* Wq = d_in[13];
  const void* bq = d_in[14];
  const void* Wk = d_in[15];
  const void* bk = d_in[16];
  const void* Wv = d_in[17];
  const void* bv = d_in[18];
  const void* Wo = d_in[19];
  const void* bo = d_in[20];

  detect_all<<<20, 256, 0, stream>>>(q, k, v, qhe, qee, khe, kee, vhe, vee,
                                     dist, edge, mraw, fraw,
                                     Wq, bq, Wk, bk, Wv, bv, Wo, bo);
  emb_prep<<<4, 256, 0, stream>>>(qhe, khe, qee, kee);
  split_prep<<<dim3(2048, 3), 256, 0, stream>>>(q, k, v);
  wt_prep<<<dim3(64, 4), 256, 0, stream>>>(Wq, Wk, Wv, Wo);

  unsigned short* inhi; hipGetSymbolAddress((void**)&inhi, HIP_SYMBOL(g_inhi));
  unsigned short* inlo; hipGetSymbolAddress((void**)&inlo, HIP_SYMBOL(g_inlo));
  unsigned short* wth;  hipGetSymbolAddress((void**)&wth,  HIP_SYMBOL(g_wth));
  unsigned short* wtl;  hipGetSymbolAddress((void**)&wtl,  HIP_SYMBOL(g_wtl));
  unsigned short* xhi;  hipGetSymbolAddress((void**)&xhi,  HIP_SYMBOL(g_xhi));
  unsigned short* xlo;  hipGetSymbolAddress((void**)&xlo,  HIP_SYMBOL(g_xlo));

  gemm_mfma<<<dim3(8, 64), 256, 0, stream>>>(inhi, inlo, wth, wtl,
                                             bq, 14, nullptr, 0);
  gemm_mfma<<<dim3(8, 64), 256, 0, stream>>>(inhi + 2097152, inlo + 2097152,
                                             wth + 262144, wtl + 262144,
                                             bk, 16, nullptr, 1);
  gemm_mfma<<<dim3(8, 64), 256, 0, stream>>>(inhi + 2 * 2097152, inlo + 2 * 2097152,
                                             wth + 2 * 262144, wtl + 2 * 262144,
                                             bv, 18, nullptr, 2);
  attn_kernel<<<2048, 256, 0, stream>>>(dist, edge, mraw, fraw, vhe, vee);
  gemm_mfma<<<dim3(8, 64), 256, 0, stream>>>(xhi, xlo,
                                             wth + 3 * 262144, wtl + 3 * 262144,
                                             bo, 20, (float*)d_out, 3);
}